// Round 3
// baseline (394.707 us; speedup 1.0000x reference)
//
#include <hip/hip_runtime.h>

#define NEG 0.2f
#define LNEPS 1e-5f

static __device__ __forceinline__ float leaky(float e){ return fmaxf(e, NEG*e); }

// pack two floats as bf16 pair (RNE), lo=a, hi=b
static __device__ __forceinline__ unsigned pack_bf16(float a, float b){
  unsigned ua = __float_as_uint(a), ub = __float_as_uint(b);
  ua += 0x7FFFu + ((ua>>16)&1u);
  ub += 0x7FFFu + ((ub>>16)&1u);
  return (ua>>16) | (ub & 0xFFFF0000u);
}
static __device__ __forceinline__ float lo_bf(unsigned u){ return __uint_as_float(u<<16); }
static __device__ __forceinline__ float hi_bf(unsigned u){ return __uint_as_float(u & 0xFFFF0000u); }

// ---------------- CSR build ----------------

__global__ __launch_bounds__(256) void k_hist(const int* __restrict__ dst, int* __restrict__ cnt, int E){
  int i = blockIdx.x*256 + threadIdx.x;
  if (i < E) atomicAdd(&cnt[dst[i]], 1);
}

__global__ __launch_bounds__(256) void k_scan1(const int* __restrict__ cnt, int* __restrict__ part, int N){
  __shared__ int sm[256];
  int b = blockIdx.x, t = threadIdx.x;
  int base = b*1024;
  int s = 0;
  #pragma unroll
  for (int j=0;j<4;++j){ int idx = base + t + j*256; if (idx < N) s += cnt[idx]; }
  sm[t]=s; __syncthreads();
  for (int off=128; off>0; off>>=1){ if (t<off) sm[t]+=sm[t+off]; __syncthreads(); }
  if (t==0) part[b]=sm[0];
}

__global__ void k_scan2(int* part, int nb){
  if (threadIdx.x==0 && blockIdx.x==0){
    int run=0;
    for (int i=0;i<nb;++i){ int v=part[i]; part[i]=run; run+=v; }
  }
}

__global__ __launch_bounds__(256) void k_scan3(const int* __restrict__ cnt, const int* __restrict__ part,
                                               int* __restrict__ off, int N, int Etot){
  __shared__ int sm[256];
  int b = blockIdx.x, t = threadIdx.x;
  int idx0 = b*1024 + t*4;
  int v[4]; int ts=0;
  #pragma unroll
  for (int j=0;j<4;++j){ int idx=idx0+j; v[j] = (idx<N)? cnt[idx] : 0; ts += v[j]; }
  sm[t]=ts; __syncthreads();
  for (int o=1;o<256;o<<=1){
    int add = (t>=o)? sm[t-o] : 0;
    __syncthreads();
    sm[t] += add;
    __syncthreads();
  }
  int excl = sm[t] - ts;
  int run = part[b] + excl;
  #pragma unroll
  for (int j=0;j<4;++j){ int idx=idx0+j; if (idx<N) off[idx]=run; run += v[j]; }
  if (b==0 && t==0) off[N] = Etot;
}

__global__ __launch_bounds__(256) void k_scatter(const int* __restrict__ src, const int* __restrict__ dst,
                                                 const int* __restrict__ off, int* __restrict__ fill,
                                                 int* __restrict__ csr, int* __restrict__ dsts, int E){
  int i = blockIdx.x*256 + threadIdx.x;
  if (i < E){
    int d = dst[i];
    int p = off[d] + atomicAdd(&fill[d], 1);
    csr[p] = src[i];
    dsts[p] = d;
  }
}

// ---------------- GEMM: O[N,128] = A[N,128] @ W[128,128] ----------------

__global__ __launch_bounds__(256) void k_gemm(const float* __restrict__ A, const float* __restrict__ W,
                                              float* __restrict__ O, int n){
  __shared__ float As[8][68];
  __shared__ float Ws[8][128];
  int tid = threadIdx.x;
  int row0 = blockIdx.x * 64;
  int tx = tid & 15;
  int ty = tid >> 4;
  float acc[4][8];
  #pragma unroll
  for (int i=0;i<4;++i)
    #pragma unroll
    for (int j=0;j<8;++j) acc[i][j]=0.f;

  for (int k0 = 0; k0 < 128; k0 += 8){
    {
      int node = tid >> 2;
      int kk = (tid & 3) * 2;
      int r = row0 + node;
      float2 v = make_float2(0.f, 0.f);
      if (r < n) v = *(const float2*)&A[(size_t)r*128 + k0 + kk];
      As[kk][node] = v.x;
      As[kk+1][node] = v.y;
    }
    {
      int kk = tid >> 5;
      int ff = (tid & 31) * 4;
      *(float4*)&Ws[kk][ff] = *(const float4*)&W[(size_t)(k0+kk)*128 + ff];
    }
    __syncthreads();
    #pragma unroll
    for (int k=0;k<8;++k){
      float4 a = *(const float4*)&As[k][ty*4];
      float4 b0 = *(const float4*)&Ws[k][tx*8];
      float4 b1 = *(const float4*)&Ws[k][tx*8+4];
      float av[4] = {a.x,a.y,a.z,a.w};
      float bv[8] = {b0.x,b0.y,b0.z,b0.w,b1.x,b1.y,b1.z,b1.w};
      #pragma unroll
      for (int i=0;i<4;++i)
        #pragma unroll
        for (int j=0;j<8;++j) acc[i][j] = fmaf(av[i], bv[j], acc[i][j]);
    }
    __syncthreads();
  }
  #pragma unroll
  for (int i=0;i<4;++i){
    int r = row0 + ty*4 + i;
    if (r < n){
      float4 o0 = make_float4(acc[i][0],acc[i][1],acc[i][2],acc[i][3]);
      float4 o1 = make_float4(acc[i][4],acc[i][5],acc[i][6],acc[i][7]);
      *(float4*)&O[(size_t)r*128 + tx*8] = o0;
      *(float4*)&O[(size_t)r*128 + tx*8 + 4] = o1;
    }
  }
}

// ---------------- attention logits + bf16 pack + self-logit m0 ----------------

__global__ __launch_bounds__(256) void k_esed4(const float* __restrict__ H, const float* __restrict__ as,
                                               const float* __restrict__ ad, float* __restrict__ es,
                                               float* __restrict__ ed, float* __restrict__ m0,
                                               unsigned* __restrict__ Hb, int N){
  int node = blockIdx.x*4 + (threadIdx.x>>6);
  int lane = threadIdx.x & 63;
  if (node >= N) return;
  int hA = lane>>5, c = lane&31;
  float v1 = H[(size_t)node*128 + lane];
  float v2 = H[(size_t)node*128 + 64 + lane];
  Hb[(size_t)node*64 + lane] = pack_bf16(v1, v2);
  float s1 = v1*as[hA*32+c], s2 = v2*as[(hA+2)*32+c];
  float d1 = v1*ad[hA*32+c], d2 = v2*ad[(hA+2)*32+c];
  #pragma unroll
  for (int m=16;m>0;m>>=1){
    s1 += __shfl_xor(s1,m); s2 += __shfl_xor(s2,m);
    d1 += __shfl_xor(d1,m); d2 += __shfl_xor(d2,m);
  }
  if (c==0){
    es[node*4+hA]   = s1; es[node*4+hA+2] = s2;
    ed[node*4+hA]   = d1; ed[node*4+hA+2] = d2;
    m0[node*4+hA]   = leaky(s1+d1);
    m0[node*4+hA+2] = leaky(s2+d2);
  }
}

__global__ __launch_bounds__(256) void k_esed1(const float* __restrict__ H, const float* __restrict__ as,
                                               const float* __restrict__ ad, float* __restrict__ es,
                                               float* __restrict__ ed, float* __restrict__ m0,
                                               unsigned* __restrict__ Hb, int N){
  int node = blockIdx.x*4 + (threadIdx.x>>6);
  int lane = threadIdx.x & 63;
  if (node >= N) return;
  float v1 = H[(size_t)node*128 + lane];
  float v2 = H[(size_t)node*128 + 64 + lane];
  Hb[(size_t)node*64 + lane] = pack_bf16(v1, v2);
  float s = v1*as[lane] + v2*as[64+lane];
  float d = v1*ad[lane] + v2*ad[64+lane];
  #pragma unroll
  for (int m=32;m>0;m>>=1){ s += __shfl_xor(s,m); d += __shfl_xor(d,m); }
  if (lane==0){ es[node]=s; ed[node]=d; m0[node]=leaky(s+d); }
}

// ---------------- edge-parallel softmax weight precompute ----------------
// layer 1: w4[i] = {w(h0), w(h2), w(h1), w(h3)} so lane (head hA) grabs a float2 pair.

__global__ __launch_bounds__(256) void k_wt4(const int* __restrict__ csr, const int* __restrict__ dsts,
                                             const float* __restrict__ es, const float* __restrict__ ed,
                                             const float* __restrict__ m0, float4* __restrict__ w4, int E){
  int i = blockIdx.x*256 + threadIdx.x;
  if (i >= E) return;
  int s = csr[i], d = dsts[i];
  float4 e4 = *(const float4*)&es[(size_t)s*4];
  float4 d4 = *(const float4*)&ed[(size_t)d*4];
  float4 q4 = *(const float4*)&m0[(size_t)d*4];
  float w0 = __expf(leaky(e4.x+d4.x) - q4.x);
  float w1 = __expf(leaky(e4.y+d4.y) - q4.y);
  float w2 = __expf(leaky(e4.z+d4.z) - q4.z);
  float w3 = __expf(leaky(e4.w+d4.w) - q4.w);
  w4[i] = make_float4(w0, w2, w1, w3);
}

__global__ __launch_bounds__(256) void k_wt1(const int* __restrict__ csr, const int* __restrict__ dsts,
                                             const float* __restrict__ es, const float* __restrict__ ed,
                                             const float* __restrict__ m0, float* __restrict__ w1, int E){
  int i = blockIdx.x*256 + threadIdx.x;
  if (i >= E) return;
  int s = csr[i], d = dsts[i];
  w1[i] = __expf(leaky(es[s] + ed[d]) - m0[d]);
}

// ---------------- aggregation + fused bias/LN/ReLU ----------------

__global__ __launch_bounds__(256) void k_agg4(const float* __restrict__ H, const unsigned* __restrict__ Hb,
                                              const float* __restrict__ wbuf,
                                              const int* __restrict__ off, const int* __restrict__ csr,
                                              const float* __restrict__ bias, const float* __restrict__ g,
                                              const float* __restrict__ be, float* __restrict__ out, int N){
  int node = blockIdx.x*4 + (threadIdx.x>>6);
  int lane = threadIdx.x & 63;
  if (node >= N) return;
  int hA = lane>>5;
  float lA = 1.f, lB = 1.f;                       // self term: exp(m0-m0)=1
  float a1 = H[(size_t)node*128 + lane];          // self row in f32
  float a2 = H[(size_t)node*128 + 64 + lane];
  int j0 = off[node], j1 = off[node+1];
  int j = j0;
  for (; j+3 < j1; j += 4){
    int s0 = __builtin_amdgcn_readfirstlane(csr[j]);
    int s1 = __builtin_amdgcn_readfirstlane(csr[j+1]);
    int s2 = __builtin_amdgcn_readfirstlane(csr[j+2]);
    int s3 = __builtin_amdgcn_readfirstlane(csr[j+3]);
    unsigned u0 = Hb[(size_t)s0*64 + lane];
    unsigned u1 = Hb[(size_t)s1*64 + lane];
    unsigned u2 = Hb[(size_t)s2*64 + lane];
    unsigned u3 = Hb[(size_t)s3*64 + lane];
    float2 w0 = *(const float2*)&wbuf[(size_t)j*4     + hA*2];
    float2 w1 = *(const float2*)&wbuf[(size_t)(j+1)*4 + hA*2];
    float2 w2 = *(const float2*)&wbuf[(size_t)(j+2)*4 + hA*2];
    float2 w3 = *(const float2*)&wbuf[(size_t)(j+3)*4 + hA*2];
    lA += (w0.x + w1.x) + (w2.x + w3.x);
    lB += (w0.y + w1.y) + (w2.y + w3.y);
    a1 = fmaf(w0.x, lo_bf(u0), a1);
    a2 = fmaf(w0.y, hi_bf(u0), a2);
    a1 = fmaf(w1.x, lo_bf(u1), a1);
    a2 = fmaf(w1.y, hi_bf(u1), a2);
    a1 = fmaf(w2.x, lo_bf(u2), a1);
    a2 = fmaf(w2.y, hi_bf(u2), a2);
    a1 = fmaf(w3.x, lo_bf(u3), a1);
    a2 = fmaf(w3.y, hi_bf(u3), a2);
  }
  for (; j < j1; ++j){
    int s0 = __builtin_amdgcn_readfirstlane(csr[j]);
    unsigned u0 = Hb[(size_t)s0*64 + lane];
    float2 w0 = *(const float2*)&wbuf[(size_t)j*4 + hA*2];
    lA += w0.x; lB += w0.y;
    a1 = fmaf(w0.x, lo_bf(u0), a1);
    a2 = fmaf(w0.y, hi_bf(u0), a2);
  }
  float v1 = a1 * __frcp_rn(lA) + bias[lane];
  float v2 = a2 * __frcp_rn(lB) + bias[64+lane];
  float s = v1 + v2;
  #pragma unroll
  for (int m=32;m>0;m>>=1) s += __shfl_xor(s,m);
  float mu = s * (1.f/128.f);
  float d1 = v1-mu, d2 = v2-mu;
  float ss = d1*d1 + d2*d2;
  #pragma unroll
  for (int m=32;m>0;m>>=1) ss += __shfl_xor(ss,m);
  float rs = rsqrtf(ss*(1.f/128.f) + LNEPS);
  out[(size_t)node*128 + lane]      = fmaxf(d1*rs*g[lane] + be[lane], 0.f);
  out[(size_t)node*128 + 64 + lane] = fmaxf(d2*rs*g[64+lane] + be[64+lane], 0.f);
}

__global__ __launch_bounds__(256) void k_agg1(const float* __restrict__ H, const unsigned* __restrict__ Hb,
                                              const float* __restrict__ wbuf,
                                              const int* __restrict__ off, const int* __restrict__ csr,
                                              const float* __restrict__ bias, const float* __restrict__ g,
                                              const float* __restrict__ be, float* __restrict__ out, int N){
  int node = blockIdx.x*4 + (threadIdx.x>>6);
  int lane = threadIdx.x & 63;
  if (node >= N) return;
  float l = 1.f;
  float a1 = H[(size_t)node*128 + lane];
  float a2 = H[(size_t)node*128 + 64 + lane];
  int j0 = off[node], j1 = off[node+1];
  int j = j0;
  for (; j+3 < j1; j += 4){
    int s0 = __builtin_amdgcn_readfirstlane(csr[j]);
    int s1 = __builtin_amdgcn_readfirstlane(csr[j+1]);
    int s2 = __builtin_amdgcn_readfirstlane(csr[j+2]);
    int s3 = __builtin_amdgcn_readfirstlane(csr[j+3]);
    unsigned u0 = Hb[(size_t)s0*64 + lane];
    unsigned u1 = Hb[(size_t)s1*64 + lane];
    unsigned u2 = Hb[(size_t)s2*64 + lane];
    unsigned u3 = Hb[(size_t)s3*64 + lane];
    float w0 = wbuf[j], w1 = wbuf[j+1], w2 = wbuf[j+2], w3 = wbuf[j+3];
    l += (w0 + w1) + (w2 + w3);
    a1 = fmaf(w0, lo_bf(u0), a1);
    a2 = fmaf(w0, hi_bf(u0), a2);
    a1 = fmaf(w1, lo_bf(u1), a1);
    a2 = fmaf(w1, hi_bf(u1), a2);
    a1 = fmaf(w2, lo_bf(u2), a1);
    a2 = fmaf(w2, hi_bf(u2), a2);
    a1 = fmaf(w3, lo_bf(u3), a1);
    a2 = fmaf(w3, hi_bf(u3), a2);
  }
  for (; j < j1; ++j){
    int s0 = __builtin_amdgcn_readfirstlane(csr[j]);
    unsigned u0 = Hb[(size_t)s0*64 + lane];
    float w0 = wbuf[j];
    l += w0;
    a1 = fmaf(w0, lo_bf(u0), a1);
    a2 = fmaf(w0, hi_bf(u0), a2);
  }
  float rl = __frcp_rn(l);
  float v1 = a1 * rl + bias[lane];
  float v2 = a2 * rl + bias[64+lane];
  float s = v1 + v2;
  #pragma unroll
  for (int mm=32;mm>0;mm>>=1) s += __shfl_xor(s,mm);
  float mu = s * (1.f/128.f);
  float d1 = v1-mu, d2 = v2-mu;
  float ss = d1*d1 + d2*d2;
  #pragma unroll
  for (int mm=32;mm>0;mm>>=1) ss += __shfl_xor(ss,mm);
  float rs = rsqrtf(ss*(1.f/128.f) + LNEPS);
  out[(size_t)node*128 + lane]      = fmaxf(d1*rs*g[lane] + be[lane], 0.f);
  out[(size_t)node*128 + 64 + lane] = fmaxf(d2*rs*g[64+lane] + be[64+lane], 0.f);
}

// ---------------- launcher ----------------

extern "C" void kernel_launch(void* const* d_in, const int* in_sizes, int n_in,
                              void* d_out, int out_size, void* d_ws, size_t ws_size,
                              hipStream_t stream){
  const float* x   = (const float*)d_in[0];
  const int*   ei  = (const int*)  d_in[1];
  const float* W1  = (const float*)d_in[2];
  const float* as1 = (const float*)d_in[3];
  const float* ad1 = (const float*)d_in[4];
  const float* b1  = (const float*)d_in[5];
  const float* W2  = (const float*)d_in[6];
  const float* as2 = (const float*)d_in[7];
  const float* ad2 = (const float*)d_in[8];
  const float* b2  = (const float*)d_in[9];
  const float* g1  = (const float*)d_in[10];
  const float* be1 = (const float*)d_in[11];
  const float* g2  = (const float*)d_in[12];
  const float* be2 = (const float*)d_in[13];

  int N = in_sizes[0] / 128;
  int E = in_sizes[1] / 2;
  const int* src = ei;
  const int* dst = ei + E;

  char* p = (char*)d_ws;
  auto carve = [&](size_t bytes)->char*{ char* r = p; p += ((bytes + 255) / 256) * 256; return r; };
  float* A    = (float*)carve((size_t)N*128*4);   // h1, then h2 (f32)
  float* B    = (float*)carve((size_t)N*128*4);   // normalized layer-1 output
  unsigned* Hb= (unsigned*)carve((size_t)N*64*4); // packed bf16 rows (reused both layers)
  float* es1 = (float*)carve((size_t)N*4*4);
  float* ed1 = (float*)carve((size_t)N*4*4);
  float* m01 = (float*)carve((size_t)N*4*4);
  float* es2 = (float*)carve((size_t)N*4);
  float* ed2 = (float*)carve((size_t)N*4);
  float* m02 = (float*)carve((size_t)N*4);
  int* cnt   = (int*)carve((size_t)N*4);
  int* off   = (int*)carve((size_t)(N+1)*4);
  int* fill  = (int*)carve((size_t)N*4);
  int* csr   = (int*)carve((size_t)E*4);
  int* dsts  = (int*)carve((size_t)E*4);
  float* w4b = (float*)carve((size_t)E*16);       // layer-1 weights, pair-ordered
  float* w1b = (float*)carve((size_t)E*4);        // layer-2 weights
  int* part  = (int*)carve(4096);

  hipMemsetAsync(cnt, 0, (size_t)N*4, stream);
  hipMemsetAsync(fill, 0, (size_t)N*4, stream);

  int eb = (E + 255) / 256;
  k_hist<<<eb, 256, 0, stream>>>(dst, cnt, E);
  int nb = (N + 1023) / 1024;
  k_scan1<<<nb, 256, 0, stream>>>(cnt, part, N);
  k_scan2<<<1, 64, 0, stream>>>(part, nb);
  k_scan3<<<nb, 256, 0, stream>>>(cnt, part, off, N, E);
  k_scatter<<<eb, 256, 0, stream>>>(src, dst, off, fill, csr, dsts, E);

  int gb = (N + 63) / 64;
  int nb4 = (N + 3) / 4;
  k_gemm<<<gb, 256, 0, stream>>>(x, W1, A, N);
  k_esed4<<<nb4, 256, 0, stream>>>(A, as1, ad1, es1, ed1, m01, Hb, N);
  k_wt4<<<eb, 256, 0, stream>>>(csr, dsts, es1, ed1, m01, (float4*)w4b, E);
  k_agg4<<<nb4, 256, 0, stream>>>(A, Hb, w4b, off, csr, b1, g1, be1, B, N);
  k_gemm<<<gb, 256, 0, stream>>>(B, W2, A, N);
  k_esed1<<<nb4, 256, 0, stream>>>(A, as2, ad2, es2, ed2, m02, Hb, N);
  k_wt1<<<eb, 256, 0, stream>>>(csr, dsts, es2, ed2, m02, w1b, E);
  k_agg1<<<nb4, 256, 0, stream>>>(A, Hb, w1b, off, csr, b2, g2, be2, (float*)d_out, N);
}

// Round 4
// 361.998 us; speedup vs baseline: 1.0904x; 1.0904x over previous
//
#include <hip/hip_runtime.h>

#define NEG 0.2f
#define LNEPS 1e-5f

static __device__ __forceinline__ float leaky(float e){ return fmaxf(e, NEG*e); }

// pack two floats as bf16 pair (RNE), lo=a, hi=b
static __device__ __forceinline__ unsigned pack_bf16(float a, float b){
  unsigned ua = __float_as_uint(a), ub = __float_as_uint(b);
  ua += 0x7FFFu + ((ua>>16)&1u);
  ub += 0x7FFFu + ((ub>>16)&1u);
  return (ua>>16) | (ub & 0xFFFF0000u);
}
static __device__ __forceinline__ float lo_bf(unsigned u){ return __uint_as_float(u<<16); }
static __device__ __forceinline__ float hi_bf(unsigned u){ return __uint_as_float(u & 0xFFFF0000u); }

// ---------------- CSR build ----------------

__global__ __launch_bounds__(256) void k_hist(const int* __restrict__ dst, int* __restrict__ cnt, int E){
  int i = blockIdx.x*256 + threadIdx.x;
  if (i < E) atomicAdd(&cnt[dst[i]], 1);
}

__global__ __launch_bounds__(256) void k_scan1(const int* __restrict__ cnt, int* __restrict__ part, int N){
  __shared__ int sm[256];
  int b = blockIdx.x, t = threadIdx.x;
  int base = b*1024;
  int s = 0;
  #pragma unroll
  for (int j=0;j<4;++j){ int idx = base + t + j*256; if (idx < N) s += cnt[idx]; }
  sm[t]=s; __syncthreads();
  for (int off=128; off>0; off>>=1){ if (t<off) sm[t]+=sm[t+off]; __syncthreads(); }
  if (t==0) part[b]=sm[0];
}

__global__ void k_scan2(int* part, int nb){
  if (threadIdx.x==0 && blockIdx.x==0){
    int run=0;
    for (int i=0;i<nb;++i){ int v=part[i]; part[i]=run; run+=v; }
  }
}

__global__ __launch_bounds__(256) void k_scan3(const int* __restrict__ cnt, const int* __restrict__ part,
                                               int* __restrict__ off, int N, int Etot){
  __shared__ int sm[256];
  int b = blockIdx.x, t = threadIdx.x;
  int idx0 = b*1024 + t*4;
  int v[4]; int ts=0;
  #pragma unroll
  for (int j=0;j<4;++j){ int idx=idx0+j; v[j] = (idx<N)? cnt[idx] : 0; ts += v[j]; }
  sm[t]=ts; __syncthreads();
  for (int o=1;o<256;o<<=1){
    int add = (t>=o)? sm[t-o] : 0;
    __syncthreads();
    sm[t] += add;
    __syncthreads();
  }
  int excl = sm[t] - ts;
  int run = part[b] + excl;
  #pragma unroll
  for (int j=0;j<4;++j){ int idx=idx0+j; if (idx<N) off[idx]=run; run += v[j]; }
  if (b==0 && t==0) off[N] = Etot;
}

// single u32 per slot: src | dst<<16 (N < 65536)
__global__ __launch_bounds__(256) void k_scatter(const int* __restrict__ src, const int* __restrict__ dst,
                                                 const int* __restrict__ off, int* __restrict__ fill,
                                                 unsigned* __restrict__ csr2, int E){
  int i = blockIdx.x*256 + threadIdx.x;
  if (i < E){
    int d = dst[i];
    int p = off[d] + atomicAdd(&fill[d], 1);
    csr2[p] = (unsigned)src[i] | ((unsigned)d << 16);
  }
}

// ---------------- fused GEMM + attention logits + bf16 pack ----------------
// O = A @ W computed in-tile; emits Hb (packed bf16), es/ed/m0. No f32 H output.

template<int HEADS>
__global__ __launch_bounds__(256) void k_gemm_fused(const float* __restrict__ A, const float* __restrict__ W,
                                                    const float* __restrict__ as, const float* __restrict__ ad,
                                                    unsigned* __restrict__ Hb, float* __restrict__ es,
                                                    float* __restrict__ ed, float* __restrict__ m0, int n){
  __shared__ float As[8][68];
  __shared__ float Ws[8][128];
  __shared__ float stage[64][136];
  __shared__ float sm_es[64][17];
  __shared__ float sm_ed[64][17];
  int tid = threadIdx.x;
  int row0 = blockIdx.x * 64;
  int tx = tid & 15;
  int ty = tid >> 4;
  float acc[4][8];
  #pragma unroll
  for (int i=0;i<4;++i)
    #pragma unroll
    for (int j=0;j<8;++j) acc[i][j]=0.f;

  for (int k0 = 0; k0 < 128; k0 += 8){
    {
      int node = tid >> 2;
      int kk = (tid & 3) * 2;
      int r = row0 + node;
      float2 v = make_float2(0.f, 0.f);
      if (r < n) v = *(const float2*)&A[(size_t)r*128 + k0 + kk];
      As[kk][node] = v.x;
      As[kk+1][node] = v.y;
    }
    {
      int kk = tid >> 5;
      int ff = (tid & 31) * 4;
      *(float4*)&Ws[kk][ff] = *(const float4*)&W[(size_t)(k0+kk)*128 + ff];
    }
    __syncthreads();
    #pragma unroll
    for (int k=0;k<8;++k){
      float4 a = *(const float4*)&As[k][ty*4];
      float4 b0 = *(const float4*)&Ws[k][tx*8];
      float4 b1 = *(const float4*)&Ws[k][tx*8+4];
      float av[4] = {a.x,a.y,a.z,a.w};
      float bv[8] = {b0.x,b0.y,b0.z,b0.w,b1.x,b1.y,b1.z,b1.w};
      #pragma unroll
      for (int i=0;i<4;++i)
        #pragma unroll
        for (int j=0;j<8;++j) acc[i][j] = fmaf(av[i], bv[j], acc[i][j]);
    }
    __syncthreads();
  }

  // epilogue: es/ed partials + stage tile to LDS
  float asv[8], adv[8];
  #pragma unroll
  for (int j=0;j<8;++j){ asv[j]=as[tx*8+j]; adv[j]=ad[tx*8+j]; }
  #pragma unroll
  for (int i=0;i<4;++i){
    float pes=0.f, ped=0.f;
    #pragma unroll
    for (int j=0;j<8;++j){ pes = fmaf(acc[i][j], asv[j], pes); ped = fmaf(acc[i][j], adv[j], ped); }
    int row = ty*4+i;
    sm_es[row][tx] = pes;
    sm_ed[row][tx] = ped;
    *(float4*)&stage[row][tx*8]   = make_float4(acc[i][0],acc[i][1],acc[i][2],acc[i][3]);
    *(float4*)&stage[row][tx*8+4] = make_float4(acc[i][4],acc[i][5],acc[i][6],acc[i][7]);
  }
  __syncthreads();
  {
    int row = tid >> 2, q = tid & 3;
    float se = (sm_es[row][q*4]+sm_es[row][q*4+1]) + (sm_es[row][q*4+2]+sm_es[row][q*4+3]);
    float sd = (sm_ed[row][q*4]+sm_ed[row][q*4+1]) + (sm_ed[row][q*4+2]+sm_ed[row][q*4+3]);
    int r = row0 + row;
    if (HEADS == 4){
      if (r < n){
        es[(size_t)r*4+q] = se; ed[(size_t)r*4+q] = sd; m0[(size_t)r*4+q] = leaky(se+sd);
      }
    } else {
      se += __shfl_xor(se,1); se += __shfl_xor(se,2);
      sd += __shfl_xor(sd,1); sd += __shfl_xor(sd,2);
      if (q == 0 && r < n){ es[r] = se; ed[r] = sd; m0[r] = leaky(se+sd); }
    }
  }
  // Hb pack: 64 rows x 64 lanes
  for (int t = tid; t < 4096; t += 256){
    int row = t >> 6, c = t & 63;
    int r = row0 + row;
    if (r < n) Hb[(size_t)r*64 + c] = pack_bf16(stage[row][c], stage[row][c+64]);
  }
}

// ---------------- edge-parallel softmax weight precompute ----------------
// layer 1: w4[i] = {w(h0), w(h2), w(h1), w(h3)} so lane (head hA) grabs a float2 pair.

__global__ __launch_bounds__(256) void k_wt4(const unsigned* __restrict__ csr2,
                                             const float* __restrict__ es, const float* __restrict__ ed,
                                             const float* __restrict__ m0, float4* __restrict__ w4, int E){
  int i = blockIdx.x*256 + threadIdx.x;
  if (i >= E) return;
  unsigned v = csr2[i];
  int s = v & 0xFFFFu, d = v >> 16;
  float4 e4 = *(const float4*)&es[(size_t)s*4];
  float4 d4 = *(const float4*)&ed[(size_t)d*4];
  float4 q4 = *(const float4*)&m0[(size_t)d*4];
  float w0 = __expf(leaky(e4.x+d4.x) - q4.x);
  float w1 = __expf(leaky(e4.y+d4.y) - q4.y);
  float w2 = __expf(leaky(e4.z+d4.z) - q4.z);
  float w3 = __expf(leaky(e4.w+d4.w) - q4.w);
  w4[i] = make_float4(w0, w2, w1, w3);
}

__global__ __launch_bounds__(256) void k_wt1(const unsigned* __restrict__ csr2,
                                             const float* __restrict__ es, const float* __restrict__ ed,
                                             const float* __restrict__ m0, float* __restrict__ w1, int E){
  int i = blockIdx.x*256 + threadIdx.x;
  if (i >= E) return;
  unsigned v = csr2[i];
  int s = v & 0xFFFFu, d = v >> 16;
  w1[i] = __expf(leaky(es[s] + ed[d]) - m0[d]);
}

// ---------------- aggregation + fused bias/LN/ReLU ----------------

__global__ __launch_bounds__(256) void k_agg4(const unsigned* __restrict__ Hb,
                                              const float* __restrict__ wbuf,
                                              const int* __restrict__ off, const unsigned* __restrict__ csr2,
                                              const float* __restrict__ bias, const float* __restrict__ g,
                                              const float* __restrict__ be, float* __restrict__ out, int N){
  int node = blockIdx.x*4 + (threadIdx.x>>6);
  int lane = threadIdx.x & 63;
  if (node >= N) return;
  int hA = lane>>5;
  float lA = 1.f, lB = 1.f;                        // self term: exp(m0-m0)=1
  unsigned uself = Hb[(size_t)node*64 + lane];
  float a1 = lo_bf(uself);
  float a2 = hi_bf(uself);
  int j0 = off[node], j1 = off[node+1];
  int j = j0;
  for (; j+3 < j1; j += 4){
    int s0 = __builtin_amdgcn_readfirstlane(csr2[j])   & 0xFFFF;
    int s1 = __builtin_amdgcn_readfirstlane(csr2[j+1]) & 0xFFFF;
    int s2 = __builtin_amdgcn_readfirstlane(csr2[j+2]) & 0xFFFF;
    int s3 = __builtin_amdgcn_readfirstlane(csr2[j+3]) & 0xFFFF;
    unsigned u0 = Hb[(size_t)s0*64 + lane];
    unsigned u1 = Hb[(size_t)s1*64 + lane];
    unsigned u2 = Hb[(size_t)s2*64 + lane];
    unsigned u3 = Hb[(size_t)s3*64 + lane];
    float2 w0 = *(const float2*)&wbuf[(size_t)j*4     + hA*2];
    float2 w1 = *(const float2*)&wbuf[(size_t)(j+1)*4 + hA*2];
    float2 w2 = *(const float2*)&wbuf[(size_t)(j+2)*4 + hA*2];
    float2 w3 = *(const float2*)&wbuf[(size_t)(j+3)*4 + hA*2];
    lA += (w0.x + w1.x) + (w2.x + w3.x);
    lB += (w0.y + w1.y) + (w2.y + w3.y);
    a1 = fmaf(w0.x, lo_bf(u0), a1);
    a2 = fmaf(w0.y, hi_bf(u0), a2);
    a1 = fmaf(w1.x, lo_bf(u1), a1);
    a2 = fmaf(w1.y, hi_bf(u1), a2);
    a1 = fmaf(w2.x, lo_bf(u2), a1);
    a2 = fmaf(w2.y, hi_bf(u2), a2);
    a1 = fmaf(w3.x, lo_bf(u3), a1);
    a2 = fmaf(w3.y, hi_bf(u3), a2);
  }
  for (; j < j1; ++j){
    int s0 = __builtin_amdgcn_readfirstlane(csr2[j]) & 0xFFFF;
    unsigned u0 = Hb[(size_t)s0*64 + lane];
    float2 w0 = *(const float2*)&wbuf[(size_t)j*4 + hA*2];
    lA += w0.x; lB += w0.y;
    a1 = fmaf(w0.x, lo_bf(u0), a1);
    a2 = fmaf(w0.y, hi_bf(u0), a2);
  }
  float v1 = a1 * __frcp_rn(lA) + bias[lane];
  float v2 = a2 * __frcp_rn(lB) + bias[64+lane];
  float s = v1 + v2;
  #pragma unroll
  for (int m=32;m>0;m>>=1) s += __shfl_xor(s,m);
  float mu = s * (1.f/128.f);
  float d1 = v1-mu, d2 = v2-mu;
  float ss = d1*d1 + d2*d2;
  #pragma unroll
  for (int m=32;m>0;m>>=1) ss += __shfl_xor(ss,m);
  float rs = rsqrtf(ss*(1.f/128.f) + LNEPS);
  out[(size_t)node*128 + lane]      = fmaxf(d1*rs*g[lane] + be[lane], 0.f);
  out[(size_t)node*128 + 64 + lane] = fmaxf(d2*rs*g[64+lane] + be[64+lane], 0.f);
}

__global__ __launch_bounds__(256) void k_agg1(const unsigned* __restrict__ Hb,
                                              const float* __restrict__ wbuf,
                                              const int* __restrict__ off, const unsigned* __restrict__ csr2,
                                              const float* __restrict__ bias, const float* __restrict__ g,
                                              const float* __restrict__ be, float* __restrict__ out, int N){
  int node = blockIdx.x*4 + (threadIdx.x>>6);
  int lane = threadIdx.x & 63;
  if (node >= N) return;
  float l = 1.f;
  unsigned uself = Hb[(size_t)node*64 + lane];
  float a1 = lo_bf(uself);
  float a2 = hi_bf(uself);
  int j0 = off[node], j1 = off[node+1];
  int j = j0;
  for (; j+3 < j1; j += 4){
    int s0 = __builtin_amdgcn_readfirstlane(csr2[j])   & 0xFFFF;
    int s1 = __builtin_amdgcn_readfirstlane(csr2[j+1]) & 0xFFFF;
    int s2 = __builtin_amdgcn_readfirstlane(csr2[j+2]) & 0xFFFF;
    int s3 = __builtin_amdgcn_readfirstlane(csr2[j+3]) & 0xFFFF;
    unsigned u0 = Hb[(size_t)s0*64 + lane];
    unsigned u1 = Hb[(size_t)s1*64 + lane];
    unsigned u2 = Hb[(size_t)s2*64 + lane];
    unsigned u3 = Hb[(size_t)s3*64 + lane];
    float w0 = wbuf[j], w1 = wbuf[j+1], w2 = wbuf[j+2], w3 = wbuf[j+3];
    l += (w0 + w1) + (w2 + w3);
    a1 = fmaf(w0, lo_bf(u0), a1);
    a2 = fmaf(w0, hi_bf(u0), a2);
    a1 = fmaf(w1, lo_bf(u1), a1);
    a2 = fmaf(w1, hi_bf(u1), a2);
    a1 = fmaf(w2, lo_bf(u2), a1);
    a2 = fmaf(w2, hi_bf(u2), a2);
    a1 = fmaf(w3, lo_bf(u3), a1);
    a2 = fmaf(w3, hi_bf(u3), a2);
  }
  for (; j < j1; ++j){
    int s0 = __builtin_amdgcn_readfirstlane(csr2[j]) & 0xFFFF;
    unsigned u0 = Hb[(size_t)s0*64 + lane];
    float w0 = wbuf[j];
    l += w0;
    a1 = fmaf(w0, lo_bf(u0), a1);
    a2 = fmaf(w0, hi_bf(u0), a2);
  }
  float rl = __frcp_rn(l);
  float v1 = a1 * rl + bias[lane];
  float v2 = a2 * rl + bias[64+lane];
  float s = v1 + v2;
  #pragma unroll
  for (int mm=32;mm>0;mm>>=1) s += __shfl_xor(s,mm);
  float mu = s * (1.f/128.f);
  float d1 = v1-mu, d2 = v2-mu;
  float ss = d1*d1 + d2*d2;
  #pragma unroll
  for (int mm=32;mm>0;mm>>=1) ss += __shfl_xor(ss,mm);
  float rs = rsqrtf(ss*(1.f/128.f) + LNEPS);
  out[(size_t)node*128 + lane]      = fmaxf(d1*rs*g[lane] + be[lane], 0.f);
  out[(size_t)node*128 + 64 + lane] = fmaxf(d2*rs*g[64+lane] + be[64+lane], 0.f);
}

// ---------------- launcher ----------------

extern "C" void kernel_launch(void* const* d_in, const int* in_sizes, int n_in,
                              void* d_out, int out_size, void* d_ws, size_t ws_size,
                              hipStream_t stream){
  const float* x   = (const float*)d_in[0];
  const int*   ei  = (const int*)  d_in[1];
  const float* W1  = (const float*)d_in[2];
  const float* as1 = (const float*)d_in[3];
  const float* ad1 = (const float*)d_in[4];
  const float* b1  = (const float*)d_in[5];
  const float* W2  = (const float*)d_in[6];
  const float* as2 = (const float*)d_in[7];
  const float* ad2 = (const float*)d_in[8];
  const float* b2  = (const float*)d_in[9];
  const float* g1  = (const float*)d_in[10];
  const float* be1 = (const float*)d_in[11];
  const float* g2  = (const float*)d_in[12];
  const float* be2 = (const float*)d_in[13];

  int N = in_sizes[0] / 128;
  int E = in_sizes[1] / 2;
  const int* src = ei;
  const int* dst = ei + E;

  char* p = (char*)d_ws;
  auto carve = [&](size_t bytes)->char*{ char* r = p; p += ((bytes + 255) / 256) * 256; return r; };
  float* B    = (float*)carve((size_t)N*128*4);   // normalized layer-1 output (f32)
  unsigned* Hb= (unsigned*)carve((size_t)N*64*4); // packed bf16 rows (reused both layers)
  float* es1 = (float*)carve((size_t)N*4*4);
  float* ed1 = (float*)carve((size_t)N*4*4);
  float* m01 = (float*)carve((size_t)N*4*4);
  float* es2 = (float*)carve((size_t)N*4);
  float* ed2 = (float*)carve((size_t)N*4);
  float* m02 = (float*)carve((size_t)N*4);
  int* cnt   = (int*)carve((size_t)N*4);
  int* off   = (int*)carve((size_t)(N+1)*4);
  int* fill  = (int*)carve((size_t)N*4);
  unsigned* csr2 = (unsigned*)carve((size_t)E*4); // src | dst<<16
  float* w4b = (float*)carve((size_t)E*16);       // layer-1 weights, pair-ordered
  float* w1b = (float*)carve((size_t)E*4);        // layer-2 weights
  int* part  = (int*)carve(4096);

  hipMemsetAsync(cnt, 0, (size_t)N*4, stream);
  hipMemsetAsync(fill, 0, (size_t)N*4, stream);

  int eb = (E + 255) / 256;
  int nb = (N + 1023) / 1024;
  int gb = (N + 63) / 64;
  int nb4 = (N + 3) / 4;

  k_hist<<<eb, 256, 0, stream>>>(dst, cnt, E);
  k_scan1<<<nb, 256, 0, stream>>>(cnt, part, N);
  k_scan2<<<1, 64, 0, stream>>>(part, nb);
  k_scan3<<<nb, 256, 0, stream>>>(cnt, part, off, N, E);
  k_gemm_fused<4><<<gb, 256, 0, stream>>>(x, W1, as1, ad1, Hb, es1, ed1, m01, N);
  k_scatter<<<eb, 256, 0, stream>>>(src, dst, off, fill, csr2, E);
  k_wt4<<<eb, 256, 0, stream>>>(csr2, es1, ed1, m01, (float4*)w4b, E);
  k_agg4<<<nb4, 256, 0, stream>>>(Hb, w4b, off, csr2, b1, g1, be1, B, N);
  k_gemm_fused<1><<<gb, 256, 0, stream>>>(B, W2, as2, ad2, Hb, es2, ed2, m02, N);
  k_wt1<<<eb, 256, 0, stream>>>(csr2, es2, ed2, m02, w1b, E);
  k_agg1<<<nb4, 256, 0, stream>>>(Hb, w1b, off, csr2, b2, g2, be2, (float*)d_out, N);
}

// Round 5
// 295.376 us; speedup vs baseline: 1.3363x; 1.2256x over previous
//
#include <hip/hip_runtime.h>

#define NEG 0.2f
#define LNEPS 1e-5f

static __device__ __forceinline__ float leaky(float e){ return fmaxf(e, NEG*e); }

// pack two floats as bf16 pair (RNE), lo=a, hi=b
static __device__ __forceinline__ unsigned pack_bf16(float a, float b){
  unsigned ua = __float_as_uint(a), ub = __float_as_uint(b);
  ua += 0x7FFFu + ((ua>>16)&1u);
  ub += 0x7FFFu + ((ub>>16)&1u);
  return (ua>>16) | (ub & 0xFFFF0000u);
}
static __device__ __forceinline__ float lo_bf(unsigned u){ return __uint_as_float(u<<16); }
static __device__ __forceinline__ float hi_bf(unsigned u){ return __uint_as_float(u & 0xFFFF0000u); }

// ================ bucketed CSR build (bucket = dst>>8) ================

// A1: coarse histogram, LDS pre-aggregated
__global__ __launch_bounds__(256) void k_bhist(const int* __restrict__ dst, int* __restrict__ bcnt, int E){
  __shared__ int h[256];
  int t = threadIdx.x;
  h[t] = 0; __syncthreads();
  int base = blockIdx.x * 4096;
  int cnt = min(4096, E - base);
  for (int i = t; i < cnt; i += 256) atomicAdd(&h[((unsigned)dst[base+i]) >> 8], 1);
  __syncthreads();
  if (h[t]) atomicAdd(&bcnt[t], h[t]);
}

// A2: scan 256 bucket counts -> boff[257]; also off[N] = E
__global__ __launch_bounds__(256) void k_bscan(const int* __restrict__ bcnt, int* __restrict__ boff,
                                               int* __restrict__ off, int N, int E){
  __shared__ int sm[256];
  int t = threadIdx.x;
  int v = bcnt[t];
  sm[t] = v; __syncthreads();
  for (int o=1;o<256;o<<=1){ int add=(t>=o)?sm[t-o]:0; __syncthreads(); sm[t]+=add; __syncthreads(); }
  boff[t+1] = sm[t];
  if (t==0){ boff[0] = 0; off[N] = E; }
}

// A3: scatter edges into bucket-grouped staging, coalesced via LDS grouping
__global__ __launch_bounds__(256) void k_bstage(const int* __restrict__ src, const int* __restrict__ dst,
                                                const int* __restrict__ boff, int* __restrict__ bfill,
                                                unsigned* __restrict__ stage, int E){
  __shared__ int h[256];
  __shared__ int sm[256];
  __shared__ int sb[256];
  __shared__ int cur[256];
  __shared__ int rb[256];
  __shared__ unsigned buf[4096];
  int t = threadIdx.x;
  h[t] = 0; __syncthreads();
  int base = blockIdx.x * 4096;
  int cnt = min(4096, E - base);
  for (int i = t; i < cnt; i += 256) atomicAdd(&h[((unsigned)dst[base+i]) >> 8], 1);
  __syncthreads();
  int hv = h[t];
  sm[t] = hv; __syncthreads();
  for (int o=1;o<256;o<<=1){ int add=(t>=o)?sm[t-o]:0; __syncthreads(); sm[t]+=add; __syncthreads(); }
  sb[t] = sm[t] - hv;
  cur[t] = sm[t] - hv;
  rb[t] = (hv > 0) ? atomicAdd(&bfill[t], hv) : 0;
  __syncthreads();
  for (int i = t; i < cnt; i += 256){
    unsigned d = (unsigned)dst[base+i];
    unsigned v = (unsigned)src[base+i] | (d << 16);
    int p = atomicAdd(&cur[d >> 8], 1);
    buf[p] = v;
  }
  __syncthreads();
  for (int i = t; i < cnt; i += 256){
    unsigned v = buf[i];
    int b = v >> 24;
    stage[ (size_t)(boff[b] + rb[b] + (i - sb[b])) ] = v;
  }
}

// B: per-bucket: per-dst offsets (writes off[] coalesced) + in-bucket permute (L2-window writes)
__global__ __launch_bounds__(256) void k_bucket(const unsigned* __restrict__ stage, const int* __restrict__ boff,
                                                int* __restrict__ off, unsigned* __restrict__ csr2, int N){
  __shared__ int cnt[256];
  __shared__ int sm[256];
  __shared__ int cur[256];
  int b = blockIdx.x, t = threadIdx.x;
  int lo = boff[b], hi = boff[b+1];
  cnt[t] = 0; __syncthreads();
  for (int i = lo + t; i < hi; i += 256) atomicAdd(&cnt[(stage[i] >> 16) & 0xFF], 1);
  __syncthreads();
  int cv = cnt[t];
  sm[t] = cv; __syncthreads();
  for (int o=1;o<256;o<<=1){ int add=(t>=o)?sm[t-o]:0; __syncthreads(); sm[t]+=add; __syncthreads(); }
  int ex = sm[t] - cv;
  cur[t] = ex;
  int d = (b << 8) + t;
  if (d < N) off[d] = lo + ex;
  __syncthreads();
  for (int i = lo + t; i < hi; i += 256){
    unsigned v = stage[i];
    int p = atomicAdd(&cur[(v >> 16) & 0xFF], 1);
    csr2[(size_t)(lo + p)] = v;
  }
}

// ================ fused GEMM + attention logits + bf16 pack ================

template<int HEADS>
__global__ __launch_bounds__(256) void k_gemm_fused(const float* __restrict__ A, const float* __restrict__ W,
                                                    const float* __restrict__ as, const float* __restrict__ ad,
                                                    unsigned* __restrict__ Hb, float* __restrict__ es,
                                                    float* __restrict__ ed, float* __restrict__ m0, int n){
  __shared__ float As[8][68];
  __shared__ float Ws[8][128];
  __shared__ float stage[64][136];
  __shared__ float sm_es[64][17];
  __shared__ float sm_ed[64][17];
  int tid = threadIdx.x;
  int row0 = blockIdx.x * 64;
  int tx = tid & 15;
  int ty = tid >> 4;
  float acc[4][8];
  #pragma unroll
  for (int i=0;i<4;++i)
    #pragma unroll
    for (int j=0;j<8;++j) acc[i][j]=0.f;

  for (int k0 = 0; k0 < 128; k0 += 8){
    {
      int node = tid >> 2;
      int kk = (tid & 3) * 2;
      int r = row0 + node;
      float2 v = make_float2(0.f, 0.f);
      if (r < n) v = *(const float2*)&A[(size_t)r*128 + k0 + kk];
      As[kk][node] = v.x;
      As[kk+1][node] = v.y;
    }
    {
      int kk = tid >> 5;
      int ff = (tid & 31) * 4;
      *(float4*)&Ws[kk][ff] = *(const float4*)&W[(size_t)(k0+kk)*128 + ff];
    }
    __syncthreads();
    #pragma unroll
    for (int k=0;k<8;++k){
      float4 a = *(const float4*)&As[k][ty*4];
      float4 b0 = *(const float4*)&Ws[k][tx*8];
      float4 b1 = *(const float4*)&Ws[k][tx*8+4];
      float av[4] = {a.x,a.y,a.z,a.w};
      float bv[8] = {b0.x,b0.y,b0.z,b0.w,b1.x,b1.y,b1.z,b1.w};
      #pragma unroll
      for (int i=0;i<4;++i)
        #pragma unroll
        for (int j=0;j<8;++j) acc[i][j] = fmaf(av[i], bv[j], acc[i][j]);
    }
    __syncthreads();
  }

  float asv[8], adv[8];
  #pragma unroll
  for (int j=0;j<8;++j){ asv[j]=as[tx*8+j]; adv[j]=ad[tx*8+j]; }
  #pragma unroll
  for (int i=0;i<4;++i){
    float pes=0.f, ped=0.f;
    #pragma unroll
    for (int j=0;j<8;++j){ pes = fmaf(acc[i][j], asv[j], pes); ped = fmaf(acc[i][j], adv[j], ped); }
    int row = ty*4+i;
    sm_es[row][tx] = pes;
    sm_ed[row][tx] = ped;
    *(float4*)&stage[row][tx*8]   = make_float4(acc[i][0],acc[i][1],acc[i][2],acc[i][3]);
    *(float4*)&stage[row][tx*8+4] = make_float4(acc[i][4],acc[i][5],acc[i][6],acc[i][7]);
  }
  __syncthreads();
  {
    int row = tid >> 2, q = tid & 3;
    float se = (sm_es[row][q*4]+sm_es[row][q*4+1]) + (sm_es[row][q*4+2]+sm_es[row][q*4+3]);
    float sd = (sm_ed[row][q*4]+sm_ed[row][q*4+1]) + (sm_ed[row][q*4+2]+sm_ed[row][q*4+3]);
    int r = row0 + row;
    if (HEADS == 4){
      if (r < n){
        es[(size_t)r*4+q] = se; ed[(size_t)r*4+q] = sd; m0[(size_t)r*4+q] = leaky(se+sd);
      }
    } else {
      se += __shfl_xor(se,1); se += __shfl_xor(se,2);
      sd += __shfl_xor(sd,1); sd += __shfl_xor(sd,2);
      if (q == 0 && r < n){ es[r] = se; ed[r] = sd; m0[r] = leaky(se+sd); }
    }
  }
  for (int t = tid; t < 4096; t += 256){
    int row = t >> 6, c = t & 63;
    int r = row0 + row;
    if (r < n) Hb[(size_t)r*64 + c] = pack_bf16(stage[row][c], stage[row][c+64]);
  }
}

// ================ aggregation (wt fused, lane-parallel) + bias/LN/ReLU ================

__global__ __launch_bounds__(256) void k_agg4(const unsigned* __restrict__ Hb,
                                              const float4* __restrict__ es4, const float4* __restrict__ ed4,
                                              const float4* __restrict__ m04,
                                              const int* __restrict__ off, const unsigned* __restrict__ csr2,
                                              const float* __restrict__ bias, const float* __restrict__ g,
                                              const float* __restrict__ be, float* __restrict__ out, int N){
  __shared__ float wlds[4][64][4];
  __shared__ int slds[4][64];
  __shared__ int s_nch;
  int wid = threadIdx.x >> 6;
  int lane = threadIdx.x & 63;
  int node = blockIdx.x*4 + wid;
  if (node >= N) node = N-1;           // keep barrier-uniform; duplicate work is benign
  int hA = lane >> 5;
  float4 edn = ed4[node];
  float4 m0n = m04[node];
  int j0 = off[node], j1 = off[node+1];
  int deg = j1 - j0;
  if (threadIdx.x == 0) s_nch = 0;
  __syncthreads();
  if (lane == 0) atomicMax(&s_nch, (deg + 63) >> 6);
  __syncthreads();
  int nch = s_nch;
  float lA = 1.f, lB = 1.f;            // self term: exp(m0-m0)=1
  unsigned uself = Hb[(size_t)node*64 + lane];
  float a1 = lo_bf(uself), a2 = hi_bf(uself);
  for (int ch = 0; ch < nch; ++ch){
    int c0 = j0 + (ch << 6);
    int m = min(64, j1 - c0);          // can be <=0 for finished waves
    if (lane < m){
      unsigned v = csr2[c0 + lane];
      int s = v & 0xFFFF;
      float4 e4 = es4[s];
      wlds[wid][lane][0] = __expf(leaky(e4.x+edn.x) - m0n.x);  // head 0
      wlds[wid][lane][1] = __expf(leaky(e4.z+edn.z) - m0n.z);  // head 2
      wlds[wid][lane][2] = __expf(leaky(e4.y+edn.y) - m0n.y);  // head 1
      wlds[wid][lane][3] = __expf(leaky(e4.w+edn.w) - m0n.w);  // head 3
      slds[wid][lane] = s;
    }
    __syncthreads();
    int j = 0;
    for (; j+3 < m; j += 4){
      int s0 = slds[wid][j], s1 = slds[wid][j+1], s2 = slds[wid][j+2], s3 = slds[wid][j+3];
      float2 w0 = *(const float2*)&wlds[wid][j][hA*2];
      float2 w1 = *(const float2*)&wlds[wid][j+1][hA*2];
      float2 w2 = *(const float2*)&wlds[wid][j+2][hA*2];
      float2 w3 = *(const float2*)&wlds[wid][j+3][hA*2];
      unsigned u0 = Hb[(size_t)s0*64 + lane];
      unsigned u1 = Hb[(size_t)s1*64 + lane];
      unsigned u2 = Hb[(size_t)s2*64 + lane];
      unsigned u3 = Hb[(size_t)s3*64 + lane];
      lA += (w0.x + w1.x) + (w2.x + w3.x);
      lB += (w0.y + w1.y) + (w2.y + w3.y);
      a1 = fmaf(w0.x, lo_bf(u0), a1); a2 = fmaf(w0.y, hi_bf(u0), a2);
      a1 = fmaf(w1.x, lo_bf(u1), a1); a2 = fmaf(w1.y, hi_bf(u1), a2);
      a1 = fmaf(w2.x, lo_bf(u2), a1); a2 = fmaf(w2.y, hi_bf(u2), a2);
      a1 = fmaf(w3.x, lo_bf(u3), a1); a2 = fmaf(w3.y, hi_bf(u3), a2);
    }
    for (; j < m; ++j){
      int s0 = slds[wid][j];
      float2 w0 = *(const float2*)&wlds[wid][j][hA*2];
      unsigned u0 = Hb[(size_t)s0*64 + lane];
      lA += w0.x; lB += w0.y;
      a1 = fmaf(w0.x, lo_bf(u0), a1); a2 = fmaf(w0.y, hi_bf(u0), a2);
    }
    __syncthreads();
  }
  float v1 = a1 * __frcp_rn(lA) + bias[lane];
  float v2 = a2 * __frcp_rn(lB) + bias[64+lane];
  float s = v1 + v2;
  #pragma unroll
  for (int m=32;m>0;m>>=1) s += __shfl_xor(s,m);
  float mu = s * (1.f/128.f);
  float d1 = v1-mu, d2 = v2-mu;
  float ss = d1*d1 + d2*d2;
  #pragma unroll
  for (int m=32;m>0;m>>=1) ss += __shfl_xor(ss,m);
  float rs = rsqrtf(ss*(1.f/128.f) + LNEPS);
  out[(size_t)node*128 + lane]      = fmaxf(d1*rs*g[lane] + be[lane], 0.f);
  out[(size_t)node*128 + 64 + lane] = fmaxf(d2*rs*g[64+lane] + be[64+lane], 0.f);
}

__global__ __launch_bounds__(256) void k_agg1(const unsigned* __restrict__ Hb,
                                              const float* __restrict__ es, const float* __restrict__ ed,
                                              const float* __restrict__ m0,
                                              const int* __restrict__ off, const unsigned* __restrict__ csr2,
                                              const float* __restrict__ bias, const float* __restrict__ g,
                                              const float* __restrict__ be, float* __restrict__ out, int N){
  __shared__ float wlds[4][64];
  __shared__ int slds[4][64];
  __shared__ int s_nch;
  int wid = threadIdx.x >> 6;
  int lane = threadIdx.x & 63;
  int node = blockIdx.x*4 + wid;
  if (node >= N) node = N-1;
  float edn = ed[node];
  float m0n = m0[node];
  int j0 = off[node], j1 = off[node+1];
  int deg = j1 - j0;
  if (threadIdx.x == 0) s_nch = 0;
  __syncthreads();
  if (lane == 0) atomicMax(&s_nch, (deg + 63) >> 6);
  __syncthreads();
  int nch = s_nch;
  float l = 1.f;
  unsigned uself = Hb[(size_t)node*64 + lane];
  float a1 = lo_bf(uself), a2 = hi_bf(uself);
  for (int ch = 0; ch < nch; ++ch){
    int c0 = j0 + (ch << 6);
    int m = min(64, j1 - c0);
    if (lane < m){
      unsigned v = csr2[c0 + lane];
      int s = v & 0xFFFF;
      wlds[wid][lane] = __expf(leaky(es[s] + edn) - m0n);
      slds[wid][lane] = s;
    }
    __syncthreads();
    int j = 0;
    for (; j+3 < m; j += 4){
      int s0 = slds[wid][j], s1 = slds[wid][j+1], s2 = slds[wid][j+2], s3 = slds[wid][j+3];
      float w0 = wlds[wid][j], w1 = wlds[wid][j+1], w2 = wlds[wid][j+2], w3 = wlds[wid][j+3];
      unsigned u0 = Hb[(size_t)s0*64 + lane];
      unsigned u1 = Hb[(size_t)s1*64 + lane];
      unsigned u2 = Hb[(size_t)s2*64 + lane];
      unsigned u3 = Hb[(size_t)s3*64 + lane];
      l += (w0 + w1) + (w2 + w3);
      a1 = fmaf(w0, lo_bf(u0), a1); a2 = fmaf(w0, hi_bf(u0), a2);
      a1 = fmaf(w1, lo_bf(u1), a1); a2 = fmaf(w1, hi_bf(u1), a2);
      a1 = fmaf(w2, lo_bf(u2), a1); a2 = fmaf(w2, hi_bf(u2), a2);
      a1 = fmaf(w3, lo_bf(u3), a1); a2 = fmaf(w3, hi_bf(u3), a2);
    }
    for (; j < m; ++j){
      int s0 = slds[wid][j];
      float w0 = wlds[wid][j];
      unsigned u0 = Hb[(size_t)s0*64 + lane];
      l += w0;
      a1 = fmaf(w0, lo_bf(u0), a1); a2 = fmaf(w0, hi_bf(u0), a2);
    }
    __syncthreads();
  }
  float rl = __frcp_rn(l);
  float v1 = a1 * rl + bias[lane];
  float v2 = a2 * rl + bias[64+lane];
  float s = v1 + v2;
  #pragma unroll
  for (int mm=32;mm>0;mm>>=1) s += __shfl_xor(s,mm);
  float mu = s * (1.f/128.f);
  float d1 = v1-mu, d2 = v2-mu;
  float ss = d1*d1 + d2*d2;
  #pragma unroll
  for (int mm=32;mm>0;mm>>=1) ss += __shfl_xor(ss,mm);
  float rs = rsqrtf(ss*(1.f/128.f) + LNEPS);
  out[(size_t)node*128 + lane]      = fmaxf(d1*rs*g[lane] + be[lane], 0.f);
  out[(size_t)node*128 + 64 + lane] = fmaxf(d2*rs*g[64+lane] + be[64+lane], 0.f);
}

// ================ launcher ================

extern "C" void kernel_launch(void* const* d_in, const int* in_sizes, int n_in,
                              void* d_out, int out_size, void* d_ws, size_t ws_size,
                              hipStream_t stream){
  const float* x   = (const float*)d_in[0];
  const int*   ei  = (const int*)  d_in[1];
  const float* W1  = (const float*)d_in[2];
  const float* as1 = (const float*)d_in[3];
  const float* ad1 = (const float*)d_in[4];
  const float* b1  = (const float*)d_in[5];
  const float* W2  = (const float*)d_in[6];
  const float* as2 = (const float*)d_in[7];
  const float* ad2 = (const float*)d_in[8];
  const float* b2  = (const float*)d_in[9];
  const float* g1  = (const float*)d_in[10];
  const float* be1 = (const float*)d_in[11];
  const float* g2  = (const float*)d_in[12];
  const float* be2 = (const float*)d_in[13];

  int N = in_sizes[0] / 128;
  int E = in_sizes[1] / 2;
  const int* src = ei;
  const int* dst = ei + E;

  char* p = (char*)d_ws;
  auto carve = [&](size_t bytes)->char*{ char* r = p; p += ((bytes + 255) / 256) * 256; return r; };
  float* B    = (float*)carve((size_t)N*128*4);   // normalized layer-1 output (f32)
  unsigned* Hb= (unsigned*)carve((size_t)N*64*4); // packed bf16 rows
  float* es1 = (float*)carve((size_t)N*4*4);
  float* ed1 = (float*)carve((size_t)N*4*4);
  float* m01 = (float*)carve((size_t)N*4*4);
  float* es2 = (float*)carve((size_t)N*4);
  float* ed2 = (float*)carve((size_t)N*4);
  float* m02 = (float*)carve((size_t)N*4);
  int* off   = (int*)carve((size_t)(N+1)*4);
  unsigned* stg = (unsigned*)carve((size_t)E*4);  // bucket-grouped staging
  unsigned* csr2= (unsigned*)carve((size_t)E*4);  // src | dst<<16, grouped by dst
  int* bcnt  = (int*)carve(256*4);
  int* bfill = (int*)carve(256*4);
  int* boff  = (int*)carve(257*4);

  hipMemsetAsync(bcnt, 0, 256*4, stream);
  hipMemsetAsync(bfill, 0, 256*4, stream);

  int nbe = (E + 4095) / 4096;
  int NB  = (N + 255) >> 8;
  int gb  = (N + 63) / 64;
  int nb4 = (N + 3) / 4;

  k_bhist <<<nbe, 256, 0, stream>>>(dst, bcnt, E);
  k_bscan <<<1,   256, 0, stream>>>(bcnt, boff, off, N, E);
  k_bstage<<<nbe, 256, 0, stream>>>(src, dst, boff, bfill, stg, E);
  k_bucket<<<NB,  256, 0, stream>>>(stg, boff, off, csr2, N);

  k_gemm_fused<4><<<gb, 256, 0, stream>>>(x, W1, as1, ad1, Hb, es1, ed1, m01, N);
  k_agg4<<<nb4, 256, 0, stream>>>(Hb, (const float4*)es1, (const float4*)ed1, (const float4*)m01,
                                  off, csr2, b1, g1, be1, B, N);
  k_gemm_fused<1><<<gb, 256, 0, stream>>>(B, W2, as2, ad2, Hb, es2, ed2, m02, N);
  k_agg1<<<nb4, 256, 0, stream>>>(Hb, es2, ed2, m02, off, csr2, b2, g2, be2, (float*)d_out, N);
}

// Round 6
// 291.133 us; speedup vs baseline: 1.3558x; 1.0146x over previous
//
#include <hip/hip_runtime.h>

#define NEG 0.2f
#define LNEPS 1e-5f

static __device__ __forceinline__ float leaky(float e){ return fmaxf(e, NEG*e); }

static __device__ __forceinline__ unsigned pack_bf16(float a, float b){
  unsigned ua = __float_as_uint(a), ub = __float_as_uint(b);
  ua += 0x7FFFu + ((ua>>16)&1u);
  ub += 0x7FFFu + ((ub>>16)&1u);
  return (ua>>16) | (ub & 0xFFFF0000u);
}
static __device__ __forceinline__ float lo_bf(unsigned u){ return __uint_as_float(u<<16); }
static __device__ __forceinline__ float hi_bf(unsigned u){ return __uint_as_float(u & 0xFFFF0000u); }

// ================ bucketed CSR build (bucket = dst>>8) ================

__global__ __launch_bounds__(256) void k_bhist(const int* __restrict__ dst, int* __restrict__ bcnt, int E){
  __shared__ int h[256];
  int t = threadIdx.x;
  h[t] = 0; __syncthreads();
  int base = blockIdx.x * 2048;
  int cnt = min(2048, E - base);
  for (int i = t; i < cnt; i += 256) atomicAdd(&h[((unsigned)dst[base+i]) >> 8], 1);
  __syncthreads();
  if (h[t]) atomicAdd(&bcnt[t], h[t]);
}

__global__ __launch_bounds__(256) void k_bscan(const int* __restrict__ bcnt, int* __restrict__ boff,
                                               int* __restrict__ off, int N, int E){
  __shared__ int sm[256];
  int t = threadIdx.x;
  int v = bcnt[t];
  sm[t] = v; __syncthreads();
  for (int o=1;o<256;o<<=1){ int add=(t>=o)?sm[t-o]:0; __syncthreads(); sm[t]+=add; __syncthreads(); }
  boff[t+1] = sm[t];
  if (t==0){ boff[0] = 0; off[N] = E; }
}

__global__ __launch_bounds__(256) void k_bstage(const int* __restrict__ src, const int* __restrict__ dst,
                                                const int* __restrict__ boff, int* __restrict__ bfill,
                                                unsigned* __restrict__ stage, int E){
  __shared__ int h[256];
  __shared__ int sm[256];
  __shared__ int sb[256];
  __shared__ int cur[256];
  __shared__ int rb[256];
  __shared__ unsigned buf[2048];
  int t = threadIdx.x;
  h[t] = 0; __syncthreads();
  int base = blockIdx.x * 2048;
  int cnt = min(2048, E - base);
  for (int i = t; i < cnt; i += 256) atomicAdd(&h[((unsigned)dst[base+i]) >> 8], 1);
  __syncthreads();
  int hv = h[t];
  sm[t] = hv; __syncthreads();
  for (int o=1;o<256;o<<=1){ int add=(t>=o)?sm[t-o]:0; __syncthreads(); sm[t]+=add; __syncthreads(); }
  sb[t] = sm[t] - hv;
  cur[t] = sm[t] - hv;
  rb[t] = (hv > 0) ? atomicAdd(&bfill[t], hv) : 0;
  __syncthreads();
  for (int i = t; i < cnt; i += 256){
    unsigned d = (unsigned)dst[base+i];
    unsigned v = (unsigned)src[base+i] | (d << 16);
    int p = atomicAdd(&cur[d >> 8], 1);
    buf[p] = v;
  }
  __syncthreads();
  for (int i = t; i < cnt; i += 256){
    unsigned v = buf[i];
    int b = v >> 24;
    stage[ (size_t)(boff[b] + rb[b] + (i - sb[b])) ] = v;
  }
}

__global__ __launch_bounds__(1024) void k_bucket(const unsigned* __restrict__ stage, const int* __restrict__ boff,
                                                 int* __restrict__ off, unsigned* __restrict__ csr2, int N){
  __shared__ int cnt[256];
  __shared__ int sm[256];
  __shared__ int cur[256];
  int b = blockIdx.x, t = threadIdx.x;
  int lo = boff[b], hi = boff[b+1];
  if (t < 256) cnt[t] = 0;
  __syncthreads();
  for (int i = lo + t; i < hi; i += 1024) atomicAdd(&cnt[(stage[i] >> 16) & 0xFF], 1);
  __syncthreads();
  if (t < 256){ sm[t] = cnt[t]; }
  __syncthreads();
  for (int o=1;o<256;o<<=1){
    int add = (t < 256 && t >= o) ? sm[t-o] : 0;
    __syncthreads();
    if (t < 256) sm[t] += add;
    __syncthreads();
  }
  if (t < 256){
    int ex = sm[t] - cnt[t];
    cur[t] = ex;
    int d = (b << 8) + t;
    if (d < N) off[d] = lo + ex;
  }
  __syncthreads();
  for (int i = lo + t; i < hi; i += 1024){
    unsigned v = stage[i];
    int p = atomicAdd(&cur[(v >> 16) & 0xFF], 1);
    csr2[(size_t)(lo + p)] = v;
  }
}

// ================ fused GEMM + attention logits + bf16 pack ================
// Hb[node*64+c] = pack(f[2c], f[2c+1]).  PACKED: A rows are bf16-packed (same pairing).

template<int HEADS, bool PACKED>
__global__ __launch_bounds__(256) void k_gemm_fused(const float* __restrict__ A, const unsigned* __restrict__ Ab,
                                                    const float* __restrict__ W,
                                                    const float* __restrict__ as, const float* __restrict__ ad,
                                                    unsigned* __restrict__ Hb, float* __restrict__ es,
                                                    float* __restrict__ ed, float* __restrict__ m0, int n){
  __shared__ float As[16][68];
  __shared__ float Ws[16][132];
  __shared__ float sm_es[64][17];
  __shared__ float sm_ed[64][17];
  int tid = threadIdx.x;
  int row0 = blockIdx.x * 64;
  int tx = tid & 15;
  int ty = tid >> 4;
  float acc[4][8];
  #pragma unroll
  for (int i=0;i<4;++i)
    #pragma unroll
    for (int j=0;j<8;++j) acc[i][j]=0.f;

  for (int k0 = 0; k0 < 128; k0 += 16){
    {
      int node = tid >> 2;
      int kk = (tid & 3) * 4;
      int r = row0 + node;
      if (PACKED){
        uint2 u = make_uint2(0u,0u);
        if (r < n) u = *(const uint2*)&Ab[(size_t)r*64 + (k0>>1) + (tid&3)*2];
        As[kk][node]   = lo_bf(u.x);
        As[kk+1][node] = hi_bf(u.x);
        As[kk+2][node] = lo_bf(u.y);
        As[kk+3][node] = hi_bf(u.y);
      } else {
        float4 v = make_float4(0.f,0.f,0.f,0.f);
        if (r < n) v = *(const float4*)&A[(size_t)r*128 + k0 + kk];
        As[kk][node]   = v.x;
        As[kk+1][node] = v.y;
        As[kk+2][node] = v.z;
        As[kk+3][node] = v.w;
      }
    }
    {
      int kk = tid >> 4;
      int ff = (tid & 15) * 8;
      *(float4*)&Ws[kk][ff]   = *(const float4*)&W[(size_t)(k0+kk)*128 + ff];
      *(float4*)&Ws[kk][ff+4] = *(const float4*)&W[(size_t)(k0+kk)*128 + ff + 4];
    }
    __syncthreads();
    #pragma unroll
    for (int k=0;k<16;++k){
      float4 a = *(const float4*)&As[k][ty*4];
      float4 b0 = *(const float4*)&Ws[k][tx*8];
      float4 b1 = *(const float4*)&Ws[k][tx*8+4];
      float av[4] = {a.x,a.y,a.z,a.w};
      float bv[8] = {b0.x,b0.y,b0.z,b0.w,b1.x,b1.y,b1.z,b1.w};
      #pragma unroll
      for (int i=0;i<4;++i)
        #pragma unroll
        for (int j=0;j<8;++j) acc[i][j] = fmaf(av[i], bv[j], acc[i][j]);
    }
    __syncthreads();
  }

  // epilogue: es/ed partials (LDS reduce) + direct packed-bf16 store from registers
  float asv[8], adv[8];
  #pragma unroll
  for (int j=0;j<8;++j){ asv[j]=as[tx*8+j]; adv[j]=ad[tx*8+j]; }
  #pragma unroll
  for (int i=0;i<4;++i){
    float pes=0.f, ped=0.f;
    #pragma unroll
    for (int j=0;j<8;++j){ pes = fmaf(acc[i][j], asv[j], pes); ped = fmaf(acc[i][j], adv[j], ped); }
    int row = ty*4+i;
    sm_es[row][tx] = pes;
    sm_ed[row][tx] = ped;
    int r = row0 + row;
    if (r < n){
      uint4 u;
      u.x = pack_bf16(acc[i][0], acc[i][1]);
      u.y = pack_bf16(acc[i][2], acc[i][3]);
      u.z = pack_bf16(acc[i][4], acc[i][5]);
      u.w = pack_bf16(acc[i][6], acc[i][7]);
      *(uint4*)&Hb[(size_t)r*64 + tx*4] = u;
    }
  }
  __syncthreads();
  {
    int row = tid >> 2, q = tid & 3;
    float se = (sm_es[row][q*4]+sm_es[row][q*4+1]) + (sm_es[row][q*4+2]+sm_es[row][q*4+3]);
    float sd = (sm_ed[row][q*4]+sm_ed[row][q*4+1]) + (sm_ed[row][q*4+2]+sm_ed[row][q*4+3]);
    int r = row0 + row;
    if (HEADS == 4){
      if (r < n){
        es[(size_t)r*4+q] = se; ed[(size_t)r*4+q] = sd; m0[(size_t)r*4+q] = leaky(se+sd);
      }
    } else {
      se += __shfl_xor(se,1); se += __shfl_xor(se,2);
      sd += __shfl_xor(sd,1); sd += __shfl_xor(sd,2);
      if (q == 0 && r < n){ es[r] = se; ed[r] = sd; m0[r] = leaky(se+sd); }
    }
  }
}

// ================ aggregation (wt fused) + bias/LN/ReLU ================
// Hb pairing (2c,2c+1): lane's two feats share one head (head = lane>>4).

template<bool OUT_PACKED>
__global__ __launch_bounds__(256) void k_agg4(const unsigned* __restrict__ Hb,
                                              const float4* __restrict__ es4, const float4* __restrict__ ed4,
                                              const float4* __restrict__ m04,
                                              const int* __restrict__ off, const unsigned* __restrict__ csr2,
                                              const float* __restrict__ bias, const float* __restrict__ g,
                                              const float* __restrict__ be, float* __restrict__ out,
                                              unsigned* __restrict__ outp, int N){
  __shared__ float wlds[4][64][4];
  __shared__ int slds[4][64];
  __shared__ int s_nch;
  int wid = threadIdx.x >> 6;
  int lane = threadIdx.x & 63;
  int node = blockIdx.x*4 + wid;
  if (node >= N) node = N-1;           // barrier-uniform; duplicate work benign
  int head = lane >> 4;
  float4 edn = ed4[node];
  float4 m0n = m04[node];
  int j0 = off[node], j1 = off[node+1];
  int deg = j1 - j0;
  if (threadIdx.x == 0) s_nch = 0;
  __syncthreads();
  if (lane == 0) atomicMax(&s_nch, (deg + 63) >> 6);
  __syncthreads();
  int nch = s_nch;
  float l = 1.f;                        // self term
  unsigned uself = Hb[(size_t)node*64 + lane];
  float a1 = lo_bf(uself), a2 = hi_bf(uself);
  for (int ch = 0; ch < nch; ++ch){
    int c0 = j0 + (ch << 6);
    int m = min(64, j1 - c0);
    if (lane < m){
      unsigned v = csr2[c0 + lane];
      int s = v & 0xFFFF;
      float4 e4 = es4[s];
      wlds[wid][lane][0] = __expf(leaky(e4.x+edn.x) - m0n.x);
      wlds[wid][lane][1] = __expf(leaky(e4.y+edn.y) - m0n.y);
      wlds[wid][lane][2] = __expf(leaky(e4.z+edn.z) - m0n.z);
      wlds[wid][lane][3] = __expf(leaky(e4.w+edn.w) - m0n.w);
      slds[wid][lane] = s;
    }
    __syncthreads();
    int j = 0;
    for (; j+3 < m; j += 4){
      int s0 = slds[wid][j], s1 = slds[wid][j+1], s2 = slds[wid][j+2], s3 = slds[wid][j+3];
      float w0 = wlds[wid][j][head];
      float w1 = wlds[wid][j+1][head];
      float w2 = wlds[wid][j+2][head];
      float w3 = wlds[wid][j+3][head];
      unsigned u0 = Hb[(size_t)s0*64 + lane];
      unsigned u1 = Hb[(size_t)s1*64 + lane];
      unsigned u2 = Hb[(size_t)s2*64 + lane];
      unsigned u3 = Hb[(size_t)s3*64 + lane];
      l += (w0 + w1) + (w2 + w3);
      a1 = fmaf(w0, lo_bf(u0), a1); a2 = fmaf(w0, hi_bf(u0), a2);
      a1 = fmaf(w1, lo_bf(u1), a1); a2 = fmaf(w1, hi_bf(u1), a2);
      a1 = fmaf(w2, lo_bf(u2), a1); a2 = fmaf(w2, hi_bf(u2), a2);
      a1 = fmaf(w3, lo_bf(u3), a1); a2 = fmaf(w3, hi_bf(u3), a2);
    }
    for (; j < m; ++j){
      int s0 = slds[wid][j];
      float w0 = wlds[wid][j][head];
      unsigned u0 = Hb[(size_t)s0*64 + lane];
      l += w0;
      a1 = fmaf(w0, lo_bf(u0), a1); a2 = fmaf(w0, hi_bf(u0), a2);
    }
    __syncthreads();
  }
  float rl = __frcp_rn(l);
  float2 bv = *(const float2*)&bias[2*lane];
  float v1 = a1 * rl + bv.x;
  float v2 = a2 * rl + bv.y;
  float s = v1 + v2;
  #pragma unroll
  for (int m=32;m>0;m>>=1) s += __shfl_xor(s,m);
  float mu = s * (1.f/128.f);
  float d1 = v1-mu, d2 = v2-mu;
  float ss = d1*d1 + d2*d2;
  #pragma unroll
  for (int m=32;m>0;m>>=1) ss += __shfl_xor(ss,m);
  float rs = rsqrtf(ss*(1.f/128.f) + LNEPS);
  float2 gv = *(const float2*)&g[2*lane];
  float2 bev = *(const float2*)&be[2*lane];
  float y1 = fmaxf(d1*rs*gv.x + bev.x, 0.f);
  float y2 = fmaxf(d2*rs*gv.y + bev.y, 0.f);
  if (OUT_PACKED){
    outp[(size_t)node*64 + lane] = pack_bf16(y1, y2);
  } else {
    *(float2*)&out[(size_t)node*128 + 2*lane] = make_float2(y1, y2);
  }
}

__global__ __launch_bounds__(256) void k_agg1(const unsigned* __restrict__ Hb,
                                              const float* __restrict__ es, const float* __restrict__ ed,
                                              const float* __restrict__ m0,
                                              const int* __restrict__ off, const unsigned* __restrict__ csr2,
                                              const float* __restrict__ bias, const float* __restrict__ g,
                                              const float* __restrict__ be, float* __restrict__ out, int N){
  __shared__ float wlds[4][64];
  __shared__ int slds[4][64];
  __shared__ int s_nch;
  int wid = threadIdx.x >> 6;
  int lane = threadIdx.x & 63;
  int node = blockIdx.x*4 + wid;
  if (node >= N) node = N-1;
  float edn = ed[node];
  float m0n = m0[node];
  int j0 = off[node], j1 = off[node+1];
  int deg = j1 - j0;
  if (threadIdx.x == 0) s_nch = 0;
  __syncthreads();
  if (lane == 0) atomicMax(&s_nch, (deg + 63) >> 6);
  __syncthreads();
  int nch = s_nch;
  float l = 1.f;
  unsigned uself = Hb[(size_t)node*64 + lane];
  float a1 = lo_bf(uself), a2 = hi_bf(uself);
  for (int ch = 0; ch < nch; ++ch){
    int c0 = j0 + (ch << 6);
    int m = min(64, j1 - c0);
    if (lane < m){
      unsigned v = csr2[c0 + lane];
      int s = v & 0xFFFF;
      wlds[wid][lane] = __expf(leaky(es[s] + edn) - m0n);
      slds[wid][lane] = s;
    }
    __syncthreads();
    int j = 0;
    for (; j+3 < m; j += 4){
      int s0 = slds[wid][j], s1 = slds[wid][j+1], s2 = slds[wid][j+2], s3 = slds[wid][j+3];
      float w0 = wlds[wid][j], w1 = wlds[wid][j+1], w2 = wlds[wid][j+2], w3 = wlds[wid][j+3];
      unsigned u0 = Hb[(size_t)s0*64 + lane];
      unsigned u1 = Hb[(size_t)s1*64 + lane];
      unsigned u2 = Hb[(size_t)s2*64 + lane];
      unsigned u3 = Hb[(size_t)s3*64 + lane];
      l += (w0 + w1) + (w2 + w3);
      a1 = fmaf(w0, lo_bf(u0), a1); a2 = fmaf(w0, hi_bf(u0), a2);
      a1 = fmaf(w1, lo_bf(u1), a1); a2 = fmaf(w1, hi_bf(u1), a2);
      a1 = fmaf(w2, lo_bf(u2), a1); a2 = fmaf(w2, hi_bf(u2), a2);
      a1 = fmaf(w3, lo_bf(u3), a1); a2 = fmaf(w3, hi_bf(u3), a2);
    }
    for (; j < m; ++j){
      int s0 = slds[wid][j];
      float w0 = wlds[wid][j];
      unsigned u0 = Hb[(size_t)s0*64 + lane];
      l += w0;
      a1 = fmaf(w0, lo_bf(u0), a1); a2 = fmaf(w0, hi_bf(u0), a2);
    }
    __syncthreads();
  }
  float rl = __frcp_rn(l);
  float2 bv = *(const float2*)&bias[2*lane];
  float v1 = a1 * rl + bv.x;
  float v2 = a2 * rl + bv.y;
  float s = v1 + v2;
  #pragma unroll
  for (int mm=32;mm>0;mm>>=1) s += __shfl_xor(s,mm);
  float mu = s * (1.f/128.f);
  float d1 = v1-mu, d2 = v2-mu;
  float ss = d1*d1 + d2*d2;
  #pragma unroll
  for (int mm=32;mm>0;mm>>=1) ss += __shfl_xor(ss,mm);
  float rs = rsqrtf(ss*(1.f/128.f) + LNEPS);
  float2 gv = *(const float2*)&g[2*lane];
  float2 bev = *(const float2*)&be[2*lane];
  float y1 = fmaxf(d1*rs*gv.x + bev.x, 0.f);
  float y2 = fmaxf(d2*rs*gv.y + bev.y, 0.f);
  *(float2*)&out[(size_t)node*128 + 2*lane] = make_float2(y1, y2);
}

// ================ launcher ================

extern "C" void kernel_launch(void* const* d_in, const int* in_sizes, int n_in,
                              void* d_out, int out_size, void* d_ws, size_t ws_size,
                              hipStream_t stream){
  const float* x   = (const float*)d_in[0];
  const int*   ei  = (const int*)  d_in[1];
  const float* W1  = (const float*)d_in[2];
  const float* as1 = (const float*)d_in[3];
  const float* ad1 = (const float*)d_in[4];
  const float* b1  = (const float*)d_in[5];
  const float* W2  = (const float*)d_in[6];
  const float* as2 = (const float*)d_in[7];
  const float* ad2 = (const float*)d_in[8];
  const float* b2  = (const float*)d_in[9];
  const float* g1  = (const float*)d_in[10];
  const float* be1 = (const float*)d_in[11];
  const float* g2  = (const float*)d_in[12];
  const float* be2 = (const float*)d_in[13];

  int N = in_sizes[0] / 128;
  int E = in_sizes[1] / 2;
  const int* src = ei;
  const int* dst = ei + E;

  char* p = (char*)d_ws;
  auto carve = [&](size_t bytes)->char*{ char* r = p; p += ((bytes + 255) / 256) * 256; return r; };
  unsigned* Hb = (unsigned*)carve((size_t)N*64*4); // packed bf16 rows (layer input features)
  unsigned* Bb = (unsigned*)carve((size_t)N*64*4); // packed bf16 normalized layer-1 output
  float* es1 = (float*)carve((size_t)N*4*4);
  float* ed1 = (float*)carve((size_t)N*4*4);
  float* m01 = (float*)carve((size_t)N*4*4);
  float* es2 = (float*)carve((size_t)N*4);
  float* ed2 = (float*)carve((size_t)N*4);
  float* m02 = (float*)carve((size_t)N*4);
  int* off   = (int*)carve((size_t)(N+1)*4);
  unsigned* stg = (unsigned*)carve((size_t)E*4);
  unsigned* csr2= (unsigned*)carve((size_t)E*4);
  int* bcnt  = (int*)carve(256*4);
  int* bfill = (int*)carve(256*4);
  int* boff  = (int*)carve(257*4);

  hipMemsetAsync(bcnt, 0, 256*4, stream);
  hipMemsetAsync(bfill, 0, 256*4, stream);

  int nbe = (E + 2047) / 2048;
  int NB  = (N + 255) >> 8;
  int gb  = (N + 63) / 64;
  int nb4 = (N + 3) / 4;

  k_bhist <<<nbe, 256, 0, stream>>>(dst, bcnt, E);
  k_bscan <<<1,   256, 0, stream>>>(bcnt, boff, off, N, E);
  k_bstage<<<nbe, 256, 0, stream>>>(src, dst, boff, bfill, stg, E);
  k_bucket<<<NB, 1024, 0, stream>>>(stg, boff, off, csr2, N);

  k_gemm_fused<4,false><<<gb, 256, 0, stream>>>(x, nullptr, W1, as1, ad1, Hb, es1, ed1, m01, N);
  k_agg4<true><<<nb4, 256, 0, stream>>>(Hb, (const float4*)es1, (const float4*)ed1, (const float4*)m01,
                                        off, csr2, b1, g1, be1, nullptr, Bb, N);
  k_gemm_fused<1,true><<<gb, 256, 0, stream>>>(nullptr, Bb, W2, as2, ad2, Hb, es2, ed2, m02, N);
  k_agg1<<<nb4, 256, 0, stream>>>(Hb, es2, ed2, m02, off, csr2, b2, g2, be2, (float*)d_out, N);
}

// Round 7
// 259.567 us; speedup vs baseline: 1.5206x; 1.1216x over previous
//
#include <hip/hip_runtime.h>

#define NEG 0.2f
#define LNEPS 1e-5f

static __device__ __forceinline__ float leaky(float e){ return fmaxf(e, NEG*e); }

static __device__ __forceinline__ unsigned pack_bf16(float a, float b){
  unsigned ua = __float_as_uint(a), ub = __float_as_uint(b);
  ua += 0x7FFFu + ((ua>>16)&1u);
  ub += 0x7FFFu + ((ub>>16)&1u);
  return (ua>>16) | (ub & 0xFFFF0000u);
}
static __device__ __forceinline__ float lo_bf(unsigned u){ return __uint_as_float(u<<16); }
static __device__ __forceinline__ float hi_bf(unsigned u){ return __uint_as_float(u & 0xFFFF0000u); }

typedef float f32x4 __attribute__((ext_vector_type(4)));
typedef short s16x8 __attribute__((ext_vector_type(8)));

union U4V8 { uint4 u; s16x8 v; };

// ================ bucketed CSR build (bucket = dst>>8) ================

__global__ __launch_bounds__(256) void k_bhist(const int* __restrict__ dst, int* __restrict__ bcnt, int E){
  __shared__ int h[256];
  int t = threadIdx.x;
  h[t] = 0; __syncthreads();
  int base = blockIdx.x * 2048;
  int cnt = min(2048, E - base);
  for (int i = t; i < cnt; i += 256) atomicAdd(&h[((unsigned)dst[base+i]) >> 8], 1);
  __syncthreads();
  if (h[t]) atomicAdd(&bcnt[t], h[t]);
}

__global__ __launch_bounds__(256) void k_bscan(const int* __restrict__ bcnt, int* __restrict__ boff,
                                               int* __restrict__ off, int N, int E){
  __shared__ int sm[256];
  int t = threadIdx.x;
  int v = bcnt[t];
  sm[t] = v; __syncthreads();
  for (int o=1;o<256;o<<=1){ int add=(t>=o)?sm[t-o]:0; __syncthreads(); sm[t]+=add; __syncthreads(); }
  boff[t+1] = sm[t];
  if (t==0){ boff[0] = 0; off[N] = E; }
}

__global__ __launch_bounds__(256) void k_bstage(const int* __restrict__ src, const int* __restrict__ dst,
                                                const int* __restrict__ boff, int* __restrict__ bfill,
                                                unsigned* __restrict__ stage, int E){
  __shared__ int h[256];
  __shared__ int sm[256];
  __shared__ int sb[256];
  __shared__ int cur[256];
  __shared__ int rb[256];
  __shared__ unsigned buf[2048];
  int t = threadIdx.x;
  h[t] = 0; __syncthreads();
  int base = blockIdx.x * 2048;
  int cnt = min(2048, E - base);
  for (int i = t; i < cnt; i += 256) atomicAdd(&h[((unsigned)dst[base+i]) >> 8], 1);
  __syncthreads();
  int hv = h[t];
  sm[t] = hv; __syncthreads();
  for (int o=1;o<256;o<<=1){ int add=(t>=o)?sm[t-o]:0; __syncthreads(); sm[t]+=add; __syncthreads(); }
  sb[t] = sm[t] - hv;
  cur[t] = sm[t] - hv;
  rb[t] = (hv > 0) ? atomicAdd(&bfill[t], hv) : 0;
  __syncthreads();
  for (int i = t; i < cnt; i += 256){
    unsigned d = (unsigned)dst[base+i];
    unsigned v = (unsigned)src[base+i] | (d << 16);
    int p = atomicAdd(&cur[d >> 8], 1);
    buf[p] = v;
  }
  __syncthreads();
  for (int i = t; i < cnt; i += 256){
    unsigned v = buf[i];
    int b = v >> 24;
    stage[ (size_t)(boff[b] + rb[b] + (i - sb[b])) ] = v;
  }
}

__global__ __launch_bounds__(1024) void k_bucket(const unsigned* __restrict__ stage, const int* __restrict__ boff,
                                                 int* __restrict__ off, unsigned* __restrict__ csr2, int N){
  __shared__ int cnt[256];
  __shared__ int sm[256];
  __shared__ int cur[256];
  int b = blockIdx.x, t = threadIdx.x;
  int lo = boff[b], hi = boff[b+1];
  if (t < 256) cnt[t] = 0;
  __syncthreads();
  for (int i = lo + t; i < hi; i += 1024) atomicAdd(&cnt[(stage[i] >> 16) & 0xFF], 1);
  __syncthreads();
  if (t < 256){ sm[t] = cnt[t]; }
  __syncthreads();
  for (int o=1;o<256;o<<=1){
    int add = (t < 256 && t >= o) ? sm[t-o] : 0;
    __syncthreads();
    if (t < 256) sm[t] += add;
    __syncthreads();
  }
  if (t < 256){
    int ex = sm[t] - cnt[t];
    cur[t] = ex;
    int d = (b << 8) + t;
    if (d < N) off[d] = lo + ex;
  }
  __syncthreads();
  for (int i = lo + t; i < hi; i += 1024){
    unsigned v = stage[i];
    int p = atomicAdd(&cur[(v >> 16) & 0xFF], 1);
    csr2[(size_t)(lo + p)] = v;
  }
}

// ================ W pre-fragmentation (B-operand order, bf16) ================
// Wb[i], i = (k0*8 + t)*64 + lane : 8 bf16 = W[k0*32 + (lane>>4)*8 + j][t*16 + (lane&15)]

__global__ __launch_bounds__(256) void k_wprep(const float* __restrict__ W, uint4* __restrict__ Wb){
  int i = blockIdx.x*256 + threadIdx.x;   // 0..2047
  int lane = i & 63, t = (i>>6)&7, k0 = i>>9;
  int c = lane & 15, q = lane >> 4;
  const float* base = &W[(size_t)(k0*32 + q*8)*128 + t*16 + c];
  uint4 u;
  u.x = pack_bf16(base[0*128], base[1*128]);
  u.y = pack_bf16(base[2*128], base[3*128]);
  u.z = pack_bf16(base[4*128], base[5*128]);
  u.w = pack_bf16(base[6*128], base[7*128]);
  Wb[i] = u;
}

// ================ MFMA GEMM + attention logits + bf16 pack ================
// 64 rows/block, 4 waves, wave handles 16 rows x 128 cols. K=128 in 4 steps of 32.
// Hb[node*64+c] = pack(f[2c], f[2c+1]).

template<int HEADS, bool PACKED>
__global__ __launch_bounds__(256) void k_gemm_mfma(const float* __restrict__ A,
                                                   const unsigned* __restrict__ Ab,
                                                   const uint4* __restrict__ Wb,
                                                   const float* __restrict__ as, const float* __restrict__ ad,
                                                   unsigned* __restrict__ Hb, float* __restrict__ es,
                                                   float* __restrict__ ed, float* __restrict__ m0, int n){
  __shared__ unsigned hstage[4][16*68];
  int tid = threadIdx.x;
  int wave = tid >> 6, lane = tid & 63;
  int c = lane & 15, q = lane >> 4;
  int r0 = blockIdx.x*64 + wave*16;
  int rowa = r0 + c;                 // a-frag row for this lane
  int rowc = min(rowa, n-1);
  f32x4 acc[8];
  #pragma unroll
  for (int t=0;t<8;++t) acc[t] = (f32x4){0.f,0.f,0.f,0.f};

  #pragma unroll
  for (int k0 = 0; k0 < 4; ++k0){
    U4V8 af;
    if (PACKED){
      af.u = *(const uint4*)&Ab[(size_t)rowc*64 + k0*16 + q*4];
    } else {
      const float* ap = &A[(size_t)rowc*128 + k0*32 + q*8];
      float4 v0 = *(const float4*)ap;
      float4 v1 = *(const float4*)(ap+4);
      af.u.x = pack_bf16(v0.x, v0.y);
      af.u.y = pack_bf16(v0.z, v0.w);
      af.u.z = pack_bf16(v1.x, v1.y);
      af.u.w = pack_bf16(v1.z, v1.w);
    }
    #pragma unroll
    for (int t=0;t<8;++t){
      U4V8 bf;
      bf.u = Wb[(k0*8+t)*64 + lane];
      acc[t] = __builtin_amdgcn_mfma_f32_16x16x32_bf16(af.v, bf.v, acc[t], 0, 0, 0);
    }
  }

  // ---- es/ed/m0 from accumulators (D row = q*4+reg, col = t*16+c) ----
  float asv[8], adv[8];
  #pragma unroll
  for (int t=0;t<8;++t){ asv[t] = as[t*16+c]; adv[t] = ad[t*16+c]; }
  if (HEADS == 4){
    float pes[4][4], ped[4][4];
    #pragma unroll
    for (int r=0;r<4;++r)
      #pragma unroll
      for (int h=0;h<4;++h){ pes[r][h]=0.f; ped[r][h]=0.f; }
    #pragma unroll
    for (int t=0;t<8;++t)
      #pragma unroll
      for (int r=0;r<4;++r){
        pes[r][t>>1] = fmaf(acc[t][r], asv[t], pes[r][t>>1]);
        ped[r][t>>1] = fmaf(acc[t][r], adv[t], ped[r][t>>1]);
      }
    #pragma unroll
    for (int r=0;r<4;++r)
      #pragma unroll
      for (int h=0;h<4;++h){
        #pragma unroll
        for (int m=1;m<16;m<<=1){
          pes[r][h] += __shfl_xor(pes[r][h], m);
          ped[r][h] += __shfl_xor(ped[r][h], m);
        }
      }
    if (c == 0){
      #pragma unroll
      for (int r=0;r<4;++r){
        int row2 = r0 + q*4 + r;
        if (row2 < n){
          float4 e = make_float4(pes[r][0],pes[r][1],pes[r][2],pes[r][3]);
          float4 d = make_float4(ped[r][0],ped[r][1],ped[r][2],ped[r][3]);
          float4 mm = make_float4(leaky(e.x+d.x),leaky(e.y+d.y),leaky(e.z+d.z),leaky(e.w+d.w));
          *(float4*)&es[(size_t)row2*4] = e;
          *(float4*)&ed[(size_t)row2*4] = d;
          *(float4*)&m0[(size_t)row2*4] = mm;
        }
      }
    }
  } else {
    float pes[4] = {0.f,0.f,0.f,0.f}, ped[4] = {0.f,0.f,0.f,0.f};
    #pragma unroll
    for (int t=0;t<8;++t)
      #pragma unroll
      for (int r=0;r<4;++r){
        pes[r] = fmaf(acc[t][r], asv[t], pes[r]);
        ped[r] = fmaf(acc[t][r], adv[t], ped[r]);
      }
    #pragma unroll
    for (int r=0;r<4;++r){
      #pragma unroll
      for (int m=1;m<16;m<<=1){
        pes[r] += __shfl_xor(pes[r], m);
        ped[r] += __shfl_xor(ped[r], m);
      }
    }
    if (c == 0){
      #pragma unroll
      for (int r=0;r<4;++r){
        int row2 = r0 + q*4 + r;
        if (row2 < n){
          es[row2] = pes[r]; ed[row2] = ped[r]; m0[row2] = leaky(pes[r]+ped[r]);
        }
      }
    }
  }

  // ---- Hb pack via per-wave LDS transpose (no barrier needed, same wave) ----
  unsigned* hs = hstage[wave];
  #pragma unroll
  for (int t=0;t<8;++t)
    #pragma unroll
    for (int r=0;r<4;++r){
      float other = __shfl_xor(acc[t][r], 1);
      if (!(c & 1)) hs[(q*4+r)*68 + t*8 + (c>>1)] = pack_bf16(acc[t][r], other);
    }
  #pragma unroll
  for (int it=0; it<4; ++it){
    int idx = it*64 + lane;          // 16 rows x 16 uint4
    int rr = idx >> 4, c4 = idx & 15;
    int grow = r0 + rr;
    if (grow < n)
      *(uint4*)&Hb[(size_t)grow*64 + c4*4] = *(uint4*)&hs[rr*68 + c4*4];
  }
}

// ================ aggregation (wt fused) + bias/LN/ReLU ================
// Hb pairing (2c,2c+1): lane's two feats share one head (head = lane>>4).

template<bool OUT_PACKED>
__global__ __launch_bounds__(256) void k_agg4(const unsigned* __restrict__ Hb,
                                              const float4* __restrict__ es4, const float4* __restrict__ ed4,
                                              const float4* __restrict__ m04,
                                              const int* __restrict__ off, const unsigned* __restrict__ csr2,
                                              const float* __restrict__ bias, const float* __restrict__ g,
                                              const float* __restrict__ be, float* __restrict__ out,
                                              unsigned* __restrict__ outp, int N){
  __shared__ float wlds[4][64][4];
  __shared__ int slds[4][64];
  __shared__ int s_nch;
  int wid = threadIdx.x >> 6;
  int lane = threadIdx.x & 63;
  int node = blockIdx.x*4 + wid;
  if (node >= N) node = N-1;
  int head = lane >> 4;
  float4 edn = ed4[node];
  float4 m0n = m04[node];
  int j0 = off[node], j1 = off[node+1];
  int deg = j1 - j0;
  if (threadIdx.x == 0) s_nch = 0;
  __syncthreads();
  if (lane == 0) atomicMax(&s_nch, (deg + 63) >> 6);
  __syncthreads();
  int nch = s_nch;
  float l = 1.f;
  unsigned uself = Hb[(size_t)node*64 + lane];
  float a1 = lo_bf(uself), a2 = hi_bf(uself);
  for (int ch = 0; ch < nch; ++ch){
    int c0 = j0 + (ch << 6);
    int m = min(64, j1 - c0);
    if (lane < m){
      unsigned v = csr2[c0 + lane];
      int s = v & 0xFFFF;
      float4 e4 = es4[s];
      wlds[wid][lane][0] = __expf(leaky(e4.x+edn.x) - m0n.x);
      wlds[wid][lane][1] = __expf(leaky(e4.y+edn.y) - m0n.y);
      wlds[wid][lane][2] = __expf(leaky(e4.z+edn.z) - m0n.z);
      wlds[wid][lane][3] = __expf(leaky(e4.w+edn.w) - m0n.w);
      slds[wid][lane] = s;
    }
    __syncthreads();
    int j = 0;
    for (; j+3 < m; j += 4){
      int s0 = slds[wid][j], s1 = slds[wid][j+1], s2 = slds[wid][j+2], s3 = slds[wid][j+3];
      float w0 = wlds[wid][j][head];
      float w1 = wlds[wid][j+1][head];
      float w2 = wlds[wid][j+2][head];
      float w3 = wlds[wid][j+3][head];
      unsigned u0 = Hb[(size_t)s0*64 + lane];
      unsigned u1 = Hb[(size_t)s1*64 + lane];
      unsigned u2 = Hb[(size_t)s2*64 + lane];
      unsigned u3 = Hb[(size_t)s3*64 + lane];
      l += (w0 + w1) + (w2 + w3);
      a1 = fmaf(w0, lo_bf(u0), a1); a2 = fmaf(w0, hi_bf(u0), a2);
      a1 = fmaf(w1, lo_bf(u1), a1); a2 = fmaf(w1, hi_bf(u1), a2);
      a1 = fmaf(w2, lo_bf(u2), a1); a2 = fmaf(w2, hi_bf(u2), a2);
      a1 = fmaf(w3, lo_bf(u3), a1); a2 = fmaf(w3, hi_bf(u3), a2);
    }
    for (; j < m; ++j){
      int s0 = slds[wid][j];
      float w0 = wlds[wid][j][head];
      unsigned u0 = Hb[(size_t)s0*64 + lane];
      l += w0;
      a1 = fmaf(w0, lo_bf(u0), a1); a2 = fmaf(w0, hi_bf(u0), a2);
    }
    __syncthreads();
  }
  float rl = __frcp_rn(l);
  float2 bv = *(const float2*)&bias[2*lane];
  float v1 = a1 * rl + bv.x;
  float v2 = a2 * rl + bv.y;
  float s = v1 + v2;
  #pragma unroll
  for (int m=32;m>0;m>>=1) s += __shfl_xor(s,m);
  float mu = s * (1.f/128.f);
  float d1 = v1-mu, d2 = v2-mu;
  float ss = d1*d1 + d2*d2;
  #pragma unroll
  for (int m=32;m>0;m>>=1) ss += __shfl_xor(ss,m);
  float rs = rsqrtf(ss*(1.f/128.f) + LNEPS);
  float2 gv = *(const float2*)&g[2*lane];
  float2 bev = *(const float2*)&be[2*lane];
  float y1 = fmaxf(d1*rs*gv.x + bev.x, 0.f);
  float y2 = fmaxf(d2*rs*gv.y + bev.y, 0.f);
  if (OUT_PACKED){
    outp[(size_t)node*64 + lane] = pack_bf16(y1, y2);
  } else {
    *(float2*)&out[(size_t)node*128 + 2*lane] = make_float2(y1, y2);
  }
}

__global__ __launch_bounds__(256) void k_agg1(const unsigned* __restrict__ Hb,
                                              const float* __restrict__ es, const float* __restrict__ ed,
                                              const float* __restrict__ m0,
                                              const int* __restrict__ off, const unsigned* __restrict__ csr2,
                                              const float* __restrict__ bias, const float* __restrict__ g,
                                              const float* __restrict__ be, float* __restrict__ out, int N){
  __shared__ float wlds[4][64];
  __shared__ int slds[4][64];
  __shared__ int s_nch;
  int wid = threadIdx.x >> 6;
  int lane = threadIdx.x & 63;
  int node = blockIdx.x*4 + wid;
  if (node >= N) node = N-1;
  float edn = ed[node];
  float m0n = m0[node];
  int j0 = off[node], j1 = off[node+1];
  int deg = j1 - j0;
  if (threadIdx.x == 0) s_nch = 0;
  __syncthreads();
  if (lane == 0) atomicMax(&s_nch, (deg + 63) >> 6);
  __syncthreads();
  int nch = s_nch;
  float l = 1.f;
  unsigned uself = Hb[(size_t)node*64 + lane];
  float a1 = lo_bf(uself), a2 = hi_bf(uself);
  for (int ch = 0; ch < nch; ++ch){
    int c0 = j0 + (ch << 6);
    int m = min(64, j1 - c0);
    if (lane < m){
      unsigned v = csr2[c0 + lane];
      int s = v & 0xFFFF;
      wlds[wid][lane] = __expf(leaky(es[s] + edn) - m0n);
      slds[wid][lane] = s;
    }
    __syncthreads();
    int j = 0;
    for (; j+3 < m; j += 4){
      int s0 = slds[wid][j], s1 = slds[wid][j+1], s2 = slds[wid][j+2], s3 = slds[wid][j+3];
      float w0 = wlds[wid][j], w1 = wlds[wid][j+1], w2 = wlds[wid][j+2], w3 = wlds[wid][j+3];
      unsigned u0 = Hb[(size_t)s0*64 + lane];
      unsigned u1 = Hb[(size_t)s1*64 + lane];
      unsigned u2 = Hb[(size_t)s2*64 + lane];
      unsigned u3 = Hb[(size_t)s3*64 + lane];
      l += (w0 + w1) + (w2 + w3);
      a1 = fmaf(w0, lo_bf(u0), a1); a2 = fmaf(w0, hi_bf(u0), a2);
      a1 = fmaf(w1, lo_bf(u1), a1); a2 = fmaf(w1, hi_bf(u1), a2);
      a1 = fmaf(w2, lo_bf(u2), a1); a2 = fmaf(w2, hi_bf(u2), a2);
      a1 = fmaf(w3, lo_bf(u3), a1); a2 = fmaf(w3, hi_bf(u3), a2);
    }
    for (; j < m; ++j){
      int s0 = slds[wid][j];
      float w0 = wlds[wid][j];
      unsigned u0 = Hb[(size_t)s0*64 + lane];
      l += w0;
      a1 = fmaf(w0, lo_bf(u0), a1); a2 = fmaf(w0, hi_bf(u0), a2);
    }
    __syncthreads();
  }
  float rl = __frcp_rn(l);
  float2 bv = *(const float2*)&bias[2*lane];
  float v1 = a1 * rl + bv.x;
  float v2 = a2 * rl + bv.y;
  float s = v1 + v2;
  #pragma unroll
  for (int mm=32;mm>0;mm>>=1) s += __shfl_xor(s,mm);
  float mu = s * (1.f/128.f);
  float d1 = v1-mu, d2 = v2-mu;
  float ss = d1*d1 + d2*d2;
  #pragma unroll
  for (int mm=32;mm>0;mm>>=1) ss += __shfl_xor(ss,mm);
  float rs = rsqrtf(ss*(1.f/128.f) + LNEPS);
  float2 gv = *(const float2*)&g[2*lane];
  float2 bev = *(const float2*)&be[2*lane];
  float y1 = fmaxf(d1*rs*gv.x + bev.x, 0.f);
  float y2 = fmaxf(d2*rs*gv.y + bev.y, 0.f);
  *(float2*)&out[(size_t)node*128 + 2*lane] = make_float2(y1, y2);
}

// ================ launcher ================

extern "C" void kernel_launch(void* const* d_in, const int* in_sizes, int n_in,
                              void* d_out, int out_size, void* d_ws, size_t ws_size,
                              hipStream_t stream){
  const float* x   = (const float*)d_in[0];
  const int*   ei  = (const int*)  d_in[1];
  const float* W1  = (const float*)d_in[2];
  const float* as1 = (const float*)d_in[3];
  const float* ad1 = (const float*)d_in[4];
  const float* b1  = (const float*)d_in[5];
  const float* W2  = (const float*)d_in[6];
  const float* as2 = (const float*)d_in[7];
  const float* ad2 = (const float*)d_in[8];
  const float* b2  = (const float*)d_in[9];
  const float* g1  = (const float*)d_in[10];
  const float* be1 = (const float*)d_in[11];
  const float* g2  = (const float*)d_in[12];
  const float* be2 = (const float*)d_in[13];

  int N = in_sizes[0] / 128;
  int E = in_sizes[1] / 2;
  const int* src = ei;
  const int* dst = ei + E;

  char* p = (char*)d_ws;
  auto carve = [&](size_t bytes)->char*{ char* r = p; p += ((bytes + 255) / 256) * 256; return r; };
  unsigned* Hb = (unsigned*)carve((size_t)N*64*4); // packed bf16 rows (layer input features)
  unsigned* Bb = (unsigned*)carve((size_t)N*64*4); // packed bf16 normalized layer-1 output
  float* es1 = (float*)carve((size_t)N*4*4);
  float* ed1 = (float*)carve((size_t)N*4*4);
  float* m01 = (float*)carve((size_t)N*4*4);
  float* es2 = (float*)carve((size_t)N*4);
  float* ed2 = (float*)carve((size_t)N*4);
  float* m02 = (float*)carve((size_t)N*4);
  int* off   = (int*)carve((size_t)(N+1)*4);
  unsigned* stg = (unsigned*)carve((size_t)E*4);
  unsigned* csr2= (unsigned*)carve((size_t)E*4);
  uint4* W1b = (uint4*)carve(2048*16);
  uint4* W2b = (uint4*)carve(2048*16);
  int* bcnt  = (int*)carve(256*4);
  int* bfill = (int*)carve(256*4);
  int* boff  = (int*)carve(257*4);

  hipMemsetAsync(bcnt, 0, 256*4, stream);
  hipMemsetAsync(bfill, 0, 256*4, stream);

  int nbe = (E + 2047) / 2048;
  int NB  = (N + 255) >> 8;
  int gb  = (N + 63) / 64;
  int nb4 = (N + 3) / 4;

  k_wprep <<<8, 256, 0, stream>>>(W1, W1b);
  k_wprep <<<8, 256, 0, stream>>>(W2, W2b);
  k_bhist <<<nbe, 256, 0, stream>>>(dst, bcnt, E);
  k_bscan <<<1,   256, 0, stream>>>(bcnt, boff, off, N, E);
  k_bstage<<<nbe, 256, 0, stream>>>(src, dst, boff, bfill, stg, E);
  k_bucket<<<NB, 1024, 0, stream>>>(stg, boff, off, csr2, N);

  k_gemm_mfma<4,false><<<gb, 256, 0, stream>>>(x, nullptr, W1b, as1, ad1, Hb, es1, ed1, m01, N);
  k_agg4<true><<<nb4, 256, 0, stream>>>(Hb, (const float4*)es1, (const float4*)ed1, (const float4*)m01,
                                        off, csr2, b1, g1, be1, nullptr, Bb, N);
  k_gemm_mfma<1,true><<<gb, 256, 0, stream>>>(nullptr, Bb, W2b, as2, ad2, Hb, es2, ed2, m02, N);
  k_agg1<<<nb4, 256, 0, stream>>>(Hb, es2, ed2, m02, off, csr2, b2, g2, be2, (float*)d_out, N);
}